// Round 9
// baseline (333.008 us; speedup 1.0000x reference)
//
#include <hip/hip_runtime.h>
#include <math.h>

typedef __bf16 bf16;
typedef __bf16 bf16x8 __attribute__((ext_vector_type(8)));
typedef __bf16 bf16x4 __attribute__((ext_vector_type(4)));
typedef _Float16 f16;
typedef _Float16 f16x8 __attribute__((ext_vector_type(8)));
typedef _Float16 f16x4 __attribute__((ext_vector_type(4)));
typedef _Float16 f16x2 __attribute__((ext_vector_type(2)));
typedef __fp16 h16x2 __attribute__((ext_vector_type(2)));
typedef float f32x4 __attribute__((ext_vector_type(4)));
typedef unsigned int u32;

#define S_LEN 2048
#define QSCALE 0.18033688011112042f   // (1/8)*log2(e), folded into Q weights+bias

#if __has_builtin(__builtin_amdgcn_exp2f)
#define EXP2(x) __builtin_amdgcn_exp2f(x)   // raw v_exp_f32, no OCML denormal guard
#else
#define EXP2(x) exp2f(x)
#endif

__device__ __forceinline__ void gload_lds16(const void* g, void* l) {
  __builtin_amdgcn_global_load_lds((const __attribute__((address_space(1))) u32*)g,
                                   (__attribute__((address_space(3))) u32*)l, 16, 0, 0);
}

// ---------------- embedding + sinusoidal PE (bf16 out only) ----------------
__global__ __launch_bounds__(256) void embed_pe(const int* __restrict__ x,
    const float* __restrict__ emb, bf16* __restrict__ zb)
{
  const int row = blockIdx.x;
  const int s = row & (S_LEN - 1);
  const int tok = x[row];
  const float* e = emb + (size_t)tok * 512;
  bf16* zbr = zb + (size_t)row * 512;
  for (int i = threadIdx.x; i < 512; i += 256) {
    float invf = __expf((float)i * (-9.210340371976184f / 512.0f));
    float ang = (float)s * invf;
    float pe = (i & 1) ? __cosf(ang) : __sinf(ang);
    zbr[i] = (bf16)(e[i] + pe);
  }
}

// ---------------- weight prep: bias (y=9) + copies (y=6..8) + LDS-tiled transposes (y=0..5) ----------------
__global__ __launch_bounds__(256) void conv_t(
    const float* __restrict__ Wo, const float* __restrict__ W1, const float* __restrict__ W2,
    const float* __restrict__ WQ, const float* __restrict__ WK, const float* __restrict__ WV,
    const float* __restrict__ WfQ, const float* __restrict__ WfK, const float* __restrict__ WfV,
    const float* __restrict__ bfQ, const float* __restrict__ bfK, const float* __restrict__ bfV,
    const float* __restrict__ bQ, const float* __restrict__ bK, const float* __restrict__ bV,
    bf16* __restrict__ wot, bf16* __restrict__ w1t, bf16* __restrict__ w2t,
    bf16* __restrict__ wqt, bf16* __restrict__ wkt, bf16* __restrict__ wvt,
    bf16* __restrict__ wfqp, bf16* __restrict__ wfkp, bf16* __restrict__ wfvp,
    float* __restrict__ bc)
{
  __shared__ float T[64][65];
  const int y = blockIdx.y, x = blockIdx.x;
  if (y == 9) {                                   // combined bias, x < 384
    int n = x * 4 + ((int)threadIdx.x >> 6);
    int lane = threadIdx.x & 63;
    int z = n >> 9, hk = n & 511, h = hk >> 6, k = hk & 63;
    const float* bf = z == 0 ? bfQ : (z == 1 ? bfK : bfV);
    const float* W  = z == 0 ? WQ  : (z == 1 ? WK  : WV);
    const float* bH = z == 0 ? bQ  : (z == 1 ? bK  : bV);
    float s = 0.f;
    for (int e = lane; e < 512; e += 64)
      s += bf[e] * W[((size_t)h * 512 + e) * 64 + k];
    #pragma unroll
    for (int m = 1; m < 64; m <<= 1) s += __shfl_xor(s, m, 64);
    if (lane == 0) {
      float v = s + bH[h * 64 + k];
      if (z == 0) v *= QSCALE;
      bc[n] = v;
    }
    return;
  }
  if (y >= 6) {
    if (x >= 256) return;
    int g = x * 256 + threadIdx.x;               // 65536 float4 per tensor
    const float* in = y == 6 ? WfQ : (y == 7 ? WfK : WfV);
    bf16* outp = y == 6 ? wfqp : (y == 7 ? wfkp : wfvp);
    float4 v = *(const float4*)(in + (size_t)g * 4);
    bf16x4 o = {(bf16)v.x, (bf16)v.y, (bf16)v.z, (bf16)v.w};
    *(bf16x4*)(outp + (size_t)g * 4) = o;
    return;
  }
  const int tx = threadIdx.x & 63, ty = threadIdx.x >> 6;
  const float* src; bf16* dst;
  int src_cols, dst_cols; float scale = 1.f;
  if (y == 0) {
    if (x >= 64) return;
    int kt = x & 7, nt = x >> 3;
    src = Wo + (size_t)(kt * 64) * 512 + nt * 64; src_cols = 512;
    dst = wot + (size_t)(nt * 64) * 512 + kt * 64; dst_cols = 512;
  } else if (y == 1) {
    if (x >= 256) return;
    int kt = x & 7, nt = x >> 3;
    src = W1 + (size_t)(kt * 64) * 2048 + nt * 64; src_cols = 2048;
    dst = w1t + (size_t)(nt * 64) * 512 + kt * 64; dst_cols = 512;
  } else if (y == 2) {
    if (x >= 256) return;
    int kt = x & 31, nt = x >> 5;
    src = W2 + (size_t)(kt * 64) * 512 + nt * 64; src_cols = 512;
    dst = w2t + (size_t)(nt * 64) * 2048 + kt * 64; dst_cols = 2048;
  } else {
    if (x >= 64) return;
    const float* W = y == 3 ? WQ : (y == 4 ? WK : WV);
    bf16* o = y == 3 ? wqt : (y == 4 ? wkt : wvt);
    if (y == 3) scale = QSCALE;
    int h = x >> 3, rt = x & 7;
    src = W + (size_t)(h * 512 + rt * 64) * 64; src_cols = 64;
    dst = o + (size_t)(h * 64) * 512 + rt * 64; dst_cols = 512;
  }
  #pragma unroll
  for (int i = 0; i < 16; i++) {
    int rr = i * 4 + ty;
    T[rr][tx] = src[(size_t)rr * src_cols + tx];
  }
  __syncthreads();
  #pragma unroll
  for (int i = 0; i < 16; i++) {
    int rr = i * 4 + ty;
    dst[(size_t)rr * dst_cols + tx] = (bf16)(T[tx][rr] * scale);
  }
}

// ---------------- weight-combine GEMMs (3 in one launch, 128x64 tiles) ----------------
__global__ __launch_bounds__(256) void gemm_comb(
    const bf16* __restrict__ wqt, const bf16* __restrict__ wkt, const bf16* __restrict__ wvt,
    const bf16* __restrict__ wfqp, const bf16* __restrict__ wfkp, const bf16* __restrict__ wfvp,
    bf16* __restrict__ wc)
{
  __shared__ bf16 As[128 * 32];
  __shared__ bf16 Bs[64 * 32];
  const int z = blockIdx.z;
  const bf16* A  = z == 0 ? wqt : (z == 1 ? wkt : wvt);
  const bf16* Bt = z == 0 ? wfqp : (z == 1 ? wfkp : wfvp);
  bf16* outb = wc + (size_t)z * 262144;
  const int tid = threadIdx.x;
  const int wave = tid >> 6, lane = tid & 63, quad = lane >> 4, l16 = lane & 15;
  const int row0 = blockIdx.x * 128, col0 = blockIdx.y * 64;
  const int wm = wave >> 1, wn = wave & 1;
  f32x4 acc[4][2] = {};

  for (int kk = 0; kk < 512; kk += 32) {
    __syncthreads();
    #pragma unroll
    for (int r = 0; r < 2; r++) {
      int c = r * 256 + tid;
      gload_lds16(A + (size_t)(row0 + (c >> 2)) * 512 + kk + (c & 3) * 8, As + c * 8);
    }
    gload_lds16(Bt + (size_t)(col0 + (tid >> 2)) * 512 + kk + (tid & 3) * 8, Bs + tid * 8);
    __syncthreads();
    bf16x8 af[4], bfr[2];
    #pragma unroll
    for (int i = 0; i < 4; i++)
      af[i] = *(const bf16x8*)(As + (wm * 64 + i * 16 + l16) * 32 + quad * 8);
    #pragma unroll
    for (int i = 0; i < 2; i++)
      bfr[i] = *(const bf16x8*)(Bs + (wn * 32 + i * 16 + l16) * 32 + quad * 8);
    #pragma unroll
    for (int mt = 0; mt < 4; mt++)
      #pragma unroll
      for (int nt = 0; nt < 2; nt++)
        acc[mt][nt] = __builtin_amdgcn_mfma_f32_16x16x32_bf16(af[mt], bfr[nt], acc[mt][nt], 0, 0, 0);
  }
  #pragma unroll
  for (int nt = 0; nt < 2; nt++) {
    int col = col0 + wn * 32 + nt * 16 + l16;
    #pragma unroll
    for (int mt = 0; mt < 4; mt++) {
      int rowb = row0 + wm * 64 + mt * 16 + quad * 4;
      #pragma unroll
      for (int i = 0; i < 4; i++)
        outb[(size_t)(rowb + i) * 512 + col] = (bf16)acc[mt][nt][i];
    }
  }
}

// ======== dbuf reg-prefetch GEMM core (128x128 tile, BK=32, 1 barrier/iter) ========
#define GEMM_CORE(A_, Bt_, K_, KK0_, ITERS_)                                            \
  bf16x8 ar0, ar1, br0, br1;                                                            \
  const int c0 = tid, c1 = 256 + tid;                                                   \
  const size_t aoff0 = (size_t)(row0 + (c0 >> 2)) * (K_) + (c0 & 3) * 8;                \
  const size_t aoff1 = (size_t)(row0 + (c1 >> 2)) * (K_) + (c1 & 3) * 8;                \
  const size_t boff0 = (size_t)(col0 + (c0 >> 2)) * (K_) + (c0 & 3) * 8;                \
  const size_t boff1 = (size_t)(col0 + (c1 >> 2)) * (K_) + (c1 & 3) * 8;                \
  ar0 = *(const bf16x8*)((A_) + aoff0 + (KK0_));                                        \
  ar1 = *(const bf16x8*)((A_) + aoff1 + (KK0_));                                        \
  br0 = *(const bf16x8*)((Bt_) + boff0 + (KK0_));                                       \
  br1 = *(const bf16x8*)((Bt_) + boff1 + (KK0_));                                       \
  for (int it = 0; it < (ITERS_); it++) {                                               \
    bf16* AsB = As[it & 1];                                                             \
    bf16* BsB = Bs[it & 1];                                                             \
    *(bf16x8*)(AsB + c0 * 8) = ar0;                                                     \
    *(bf16x8*)(AsB + c1 * 8) = ar1;                                                     \
    *(bf16x8*)(BsB + c0 * 8) = br0;                                                     \
    *(bf16x8*)(BsB + c1 * 8) = br1;                                                     \
    __syncthreads();                                                                    \
    if (it + 1 < (ITERS_)) {                                                            \
      int kk = (KK0_) + (it + 1) * 32;                                                  \
      ar0 = *(const bf16x8*)((A_) + aoff0 + kk);                                        \
      ar1 = *(const bf16x8*)((A_) + aoff1 + kk);                                        \
      br0 = *(const bf16x8*)((Bt_) + boff0 + kk);                                      \
      br1 = *(const bf16x8*)((Bt_) + boff1 + kk);                                      \
    }                                                                                   \
    bf16x8 af[4], bfr[4];                                                               \
    _Pragma("unroll")                                                                   \
    for (int i = 0; i < 4; i++)                                                         \
      af[i] = *(const bf16x8*)(AsB + (wm * 64 + i * 16 + l16) * 32 + quad * 8);         \
    _Pragma("unroll")                                                                   \
    for (int i = 0; i < 4; i++)                                                         \
      bfr[i] = *(const bf16x8*)(BsB + (wn * 64 + i * 16 + l16) * 32 + quad * 8);        \
    _Pragma("unroll")                                                                   \
    for (int mt = 0; mt < 4; mt++)                                                      \
      _Pragma("unroll")                                                                 \
      for (int nt = 0; nt < 4; nt++)                                                    \
        acc[mt][nt] = __builtin_amdgcn_mfma_f32_16x16x32_bf16(af[mt], bfr[nt], acc[mt][nt], 0, 0, 0); \
  }

// ---------------- GEMM 128x128 (bias, optional relu, bf16 out; FFN1) ----------------
__global__ __launch_bounds__(256) void gemm_bt(
    const bf16* __restrict__ A, const bf16* __restrict__ Bt,
    const float* __restrict__ bias, bf16* __restrict__ outb,
    int M, int N, int K, int relu)
{
  __shared__ bf16 As[2][4096];
  __shared__ bf16 Bs[2][4096];
  const int tid = threadIdx.x;
  const int wave = tid >> 6, lane = tid & 63, quad = lane >> 4, l16 = lane & 15;
  const int row0 = blockIdx.x * 128, col0 = blockIdx.y * 128;
  const int wm = wave >> 1, wn = wave & 1;
  f32x4 acc[4][4] = {};
  GEMM_CORE(A, Bt, K, 0, K / 32)

  #pragma unroll
  for (int nt = 0; nt < 4; nt++) {
    int col = col0 + wn * 64 + nt * 16 + l16;
    float bv = bias[col];
    #pragma unroll
    for (int mt = 0; mt < 4; mt++) {
      int rowb = row0 + wm * 64 + mt * 16 + quad * 4;
      #pragma unroll
      for (int i = 0; i < 4; i++) {
        float v = acc[mt][nt][i] + bv;
        if (relu) v = fmaxf(v, 0.f);
        outb[(size_t)(rowb + i) * N + col] = (bf16)v;
      }
    }
  }
}

// ---------------- QKV GEMM: N=1536, qk f16[row][1024] + Vt f16[bh][dv][2048] ----------------
// V-block epilogue stages through XOR-swizzled LDS so Vt writes are 256B-contiguous along s
// (old path: 8B scatter at 4KB stride -> ~8x write amplification).
__global__ __launch_bounds__(256) void gemm_qkv(
    const bf16* __restrict__ A, const bf16* __restrict__ Bt,
    const float* __restrict__ bias, f16* __restrict__ qk, f16* __restrict__ Vt)
{
  __shared__ char ldsbuf[32768];
  bf16 (*As)[4096] = (bf16(*)[4096])ldsbuf;
  bf16 (*Bs)[4096] = (bf16(*)[4096])(ldsbuf + 16384);
  const int tid = threadIdx.x;
  const int wave = tid >> 6, lane = tid & 63, quad = lane >> 4, l16 = lane & 15;
  const int row0 = blockIdx.x * 128, col0 = blockIdx.y * 128;
  const int wm = wave >> 1, wn = wave & 1;
  f32x4 acc[4][4] = {};
  GEMM_CORE(A, Bt, 512, 0, 16)

  if (col0 >= 1024) {
    // V path: transpose 128 cols x 128 rows through LDS, coalesced Vt writes
    f16* Vst = (f16*)ldsbuf;                     // [128 cols][128 rows], chunk-XOR swizzled
    const int h0 = (col0 - 1024) >> 6;
    const int b = row0 >> 11, s0 = row0 & 2047;
    __syncthreads();                             // main-loop LDS reads complete
    #pragma unroll
    for (int nt = 0; nt < 4; nt++) {
      int c = wn * 64 + nt * 16 + l16;
      float bv = bias[col0 + c];
      #pragma unroll
      for (int mt = 0; mt < 4; mt++) {
        int chunk = wm * 16 + mt * 4 + quad;     // r = chunk*4 + i
        f16x4 vv;
        #pragma unroll
        for (int i = 0; i < 4; i++) vv[i] = (f16)(acc[mt][nt][i] + bv);
        *(f16x4*)(Vst + c * 128 + ((chunk ^ ((c & 7) << 2)) * 4)) = vv;
      }
    }
    __syncthreads();
    #pragma unroll
    for (int p = 0; p < 16; p++) {
      int c = p * 8 + (tid >> 5);
      int ch = tid & 31;
      f16x4 vv = *(const f16x4*)(Vst + c * 128 + ((ch ^ ((c & 7) << 2)) * 4));
      int h = h0 + (c >> 6), dv = c & 63;
      *(f16x4*)(Vt + ((size_t)((b * 8 + h) * 64 + dv)) * 2048 + s0 + ch * 4) = vv;
    }
    return;
  }

  #pragma unroll
  for (int nt = 0; nt < 4; nt++) {
    int col = col0 + wn * 64 + nt * 16 + l16;
    float bv = bias[col];
    #pragma unroll
    for (int mt = 0; mt < 4; mt++) {
      int rowb = row0 + wm * 64 + mt * 16 + quad * 4;
      #pragma unroll
      for (int i = 0; i < 4; i++)
        qk[(size_t)(rowb + i) * 1024 + col] = (f16)(acc[mt][nt][i] + bv);
    }
  }
}

// ---------------- split-K partial GEMM -> bf16 partials (FFN2, 4-way) ----------------
__global__ __launch_bounds__(256) void gemm_part(
    const bf16* __restrict__ A, const bf16* __restrict__ Bt,
    bf16* __restrict__ Pa, bf16* __restrict__ Pb,
    bf16* __restrict__ Pc, bf16* __restrict__ Pd, int N, int K, int Kh)
{
  __shared__ bf16 As[2][4096];
  __shared__ bf16 Bs[2][4096];
  const int tid = threadIdx.x;
  const int wave = tid >> 6, lane = tid & 63, quad = lane >> 4, l16 = lane & 15;
  const int row0 = blockIdx.x * 128, col0 = blockIdx.y * 128;
  const int wm = wave >> 1, wn = wave & 1;
  const int kk0 = blockIdx.z * Kh;
  bf16* P = blockIdx.z == 0 ? Pa : (blockIdx.z == 1 ? Pb : (blockIdx.z == 2 ? Pc : Pd));
  f32x4 acc[4][4] = {};
  GEMM_CORE(A, Bt, K, kk0, Kh / 32)

  #pragma unroll
  for (int nt = 0; nt < 4; nt++) {
    int col = col0 + wn * 64 + nt * 16 + l16;
    #pragma unroll
    for (int mt = 0; mt < 4; mt++) {
      int rowb = row0 + wm * 64 + mt * 16 + quad * 4;
      #pragma unroll
      for (int i = 0; i < 4; i++)
        P[(size_t)(rowb + i) * N + col] = (bf16)acc[mt][nt][i];
    }
  }
}

// ---------------- Wo GEMM with fused attention-partial merge ----------------
__global__ __launch_bounds__(256) void gemm_wo(
    const bf16* __restrict__ Op, const float* __restrict__ Rp,
    const bf16* __restrict__ Bt, bf16* __restrict__ Pa, bf16* __restrict__ Pb)
{
  __shared__ bf16 As[2][4096];
  __shared__ bf16 Bs[2][4096];
  const int tid = threadIdx.x;
  const int wave = tid >> 6, lane = tid & 63, quad = lane >> 4, l16 = lane & 15;
  const int row0 = blockIdx.x * 128, col0 = blockIdx.y * 128;
  const int wm = wave >> 1, wn = wave & 1;
  const int kk0 = blockIdx.z * 256;
  bf16* P = blockIdx.z ? Pb : Pa;
  f32x4 acc[4][4] = {};

  const int c0 = tid, c1 = 256 + tid;
  const int r0 = row0 + (c0 >> 2), r1 = r0 + 64;
  const int b0 = r0 >> 11, s0 = r0 & 2047;
  const int b1 = r1 >> 11, s1 = r1 & 2047;
  const int ccol = (c0 & 3) * 8;
  const int h0 = kk0 >> 6;
  const size_t boff0 = (size_t)(col0 + (c0 >> 2)) * 512 + ccol;
  const size_t boff1 = (size_t)(col0 + 64 + (c0 >> 2)) * 512 + ccol;

  float inv0[4], inv1[4];
  #pragma unroll
  for (int hh = 0; hh < 4; hh++) {
    int hg = h0 + hh;
    int ra = (b0 * 8 + hg) * 2048 + s0;
    float r = (Rp[ra] + Rp[65536 + ra]) + (Rp[131072 + ra] + Rp[196608 + ra]);
    inv0[hh] = 1.f / r;
    int rb = (b1 * 8 + hg) * 2048 + s1;
    r = (Rp[rb] + Rp[65536 + rb]) + (Rp[131072 + rb] + Rp[196608 + rb]);
    inv1[hh] = 1.f / r;
  }

  bf16x8 p0q[4], p1q[4], br0, br1;
  {
    int hg = h0, dv = ccol;
    size_t ia0 = ((size_t)(b0 * 8 + hg) * 2048 + s0) * 64 + dv;
    size_t ia1 = ((size_t)(b1 * 8 + hg) * 2048 + s1) * 64 + dv;
    #pragma unroll
    for (int q = 0; q < 4; q++) {
      p0q[q] = *(const bf16x8*)(Op + q * 4194304ull + ia0);
      p1q[q] = *(const bf16x8*)(Op + q * 4194304ull + ia1);
    }
    br0 = *(const bf16x8*)(Bt + boff0 + kk0);
    br1 = *(const bf16x8*)(Bt + boff1 + kk0);
  }

  for (int it = 0; it < 8; it++) {
    bf16* AsB = As[it & 1];
    bf16* BsB = Bs[it & 1];
    const float iv0 = inv0[it >> 1], iv1 = inv1[it >> 1];
    bf16x8 a0v, a1v;
    #pragma unroll
    for (int i = 0; i < 8; i++) {
      float v0 = ((float)p0q[0][i] + (float)p0q[1][i]) + ((float)p0q[2][i] + (float)p0q[3][i]);
      float v1 = ((float)p1q[0][i] + (float)p1q[1][i]) + ((float)p1q[2][i] + (float)p1q[3][i]);
      a0v[i] = (bf16)(v0 * iv0);
      a1v[i] = (bf16)(v1 * iv1);
    }
    *(bf16x8*)(AsB + c0 * 8) = a0v;
    *(bf16x8*)(AsB + c1 * 8) = a1v;
    *(bf16x8*)(BsB + c0 * 8) = br0;
    *(bf16x8*)(BsB + c1 * 8) = br1;
    __syncthreads();
    if (it < 7) {
      int itn = it + 1;
      int kk = kk0 + itn * 32;
      int hg = h0 + (itn >> 1);
      int dv = (itn & 1) * 32 + ccol;
      size_t ia0 = ((size_t)(b0 * 8 + hg) * 2048 + s0) * 64 + dv;
      size_t ia1 = ((size_t)(b1 * 8 + hg) * 2048 + s1) * 64 + dv;
      #pragma unroll
      for (int q = 0; q < 4; q++) {
        p0q[q] = *(const bf16x8*)(Op + q * 4194304ull + ia0);
        p1q[q] = *(const bf16x8*)(Op + q * 4194304ull + ia1);
      }
      br0 = *(const bf16x8*)(Bt + boff0 + kk);
      br1 = *(const bf16x8*)(Bt + boff1 + kk);
    }
    bf16x8 af[4], bfr[4];
    #pragma unroll
    for (int i = 0; i < 4; i++)
      af[i] = *(const bf16x8*)(AsB + (wm * 64 + i * 16 + l16) * 32 + quad * 8);
    #pragma unroll
    for (int i = 0; i < 4; i++)
      bfr[i] = *(const bf16x8*)(BsB + (wn * 64 + i * 16 + l16) * 32 + quad * 8);
    #pragma unroll
    for (int mt = 0; mt < 4; mt++)
      #pragma unroll
      for (int nt = 0; nt < 4; nt++)
        acc[mt][nt] = __builtin_amdgcn_mfma_f32_16x16x32_bf16(af[mt], bfr[nt], acc[mt][nt], 0, 0, 0);
  }

  #pragma unroll
  for (int nt = 0; nt < 4; nt++) {
    int col = col0 + wn * 64 + nt * 16 + l16;
    #pragma unroll
    for (int mt = 0; mt < 4; mt++) {
      int rowb = row0 + wm * 64 + mt * 16 + quad * 4;
      #pragma unroll
      for (int i = 0; i < 4; i++)
        P[(size_t)(rowb + i) * 512 + col] = (bf16)acc[mt][nt][i];
    }
  }
}

// ---------------- flash attention: 32 q/wave, split-K 4, dbuf, rsum via ones-MFMA ----------------
// qk: [8192][1024] f16; Vt: [32 bh][64 dv][2048 s] f16. Grid (16 qtile, 16 bh, 4 quarter) x2
// launches (bh0 = 0, 16) -- split purely so the profiler's top-5 reveals the non-flash kernels.
__global__ __launch_bounds__(256, 2) void flash_attn(
    const f16* __restrict__ qk, const f16* __restrict__ Vt,
    bf16* __restrict__ Op, float* __restrict__ Rp, int bh0)
{
  __shared__ f16 Ks[2][4096];   // [key][dk], 16B chunks XOR-swizzled by row&7
  __shared__ f16 Vs[2][4096];   // [dv][key], same swizzle
  const int bh = blockIdx.y + bh0, b = bh >> 3, h = bh & 7;
  const int q0 = blockIdx.x * 128;
  const int quarter = blockIdx.z;
  const int tid = threadIdx.x;
  const int wave = tid >> 6, lane = tid & 63, quad = lane >> 4, l16 = lane & 15;

  const f16* Qb = qk + ((size_t)b * S_LEN) * 1024 + h * 64;
  const f16* Kb = Qb + 512;
  const f16* Vtb = Vt + ((size_t)bh * 64) * 2048;
  const int key0 = quarter * 512;

  f16x8 qf[2][2];
  #pragma unroll
  for (int f = 0; f < 2; f++) {
    int qrow = q0 + wave * 32 + f * 16 + l16;
    #pragma unroll
    for (int kh = 0; kh < 2; kh++)
      qf[f][kh] = *(const f16x8*)(Qb + (size_t)qrow * 1024 + kh * 32 + quad * 8);
  }

  f32x4 O[2][4] = {};            // [f][mt]: O^T row=dv, col=q
  f32x4 Osum[2] = {};            // rsum accumulator via ones-MFMA
  const f16x4 onesA = {(f16)1.f, (f16)1.f, (f16)1.f, (f16)1.f};
  const int swz = l16 & 7;

  f16x8 kreg[2], vreg[2];
  const int srow = tid >> 3, soff = tid & 7;
  const int srow1 = srow + 32;

  {
    int kb = key0;
    kreg[0] = *(const f16x8*)(Kb + (size_t)(kb + srow) * 1024 + soff * 8);
    vreg[0] = *(const f16x8*)(Vtb + (size_t)srow * 2048 + kb + soff * 8);
    kreg[1] = *(const f16x8*)(Kb + (size_t)(kb + srow1) * 1024 + soff * 8);
    vreg[1] = *(const f16x8*)(Vtb + (size_t)srow1 * 2048 + kb + soff * 8);
  }

  for (int c = 0; c < 8; c++) {
    f16* KsB = Ks[c & 1];
    f16* VsB = Vs[c & 1];
    *(f16x8*)(KsB + srow * 64 + ((soff ^ (srow & 7)) * 8)) = kreg[0];
    *(f16x8*)(VsB + srow * 64 + ((soff ^ (srow & 7)) * 8)) = vreg[0];
    *(f16x8*)(KsB + srow1 * 64 + ((soff ^ (srow1 & 7)) * 8)) = kreg[1];
    *(f16x8*)(VsB + srow1 * 64 + ((soff ^ (srow1 & 7)) * 8)) = vreg[1];
    __syncthreads();
    if (c < 7) {
      int kb = key0 + (c + 1) * 64;
      kreg[0] = *(const f16x8*)(Kb + (size_t)(kb + srow) * 1024 + soff * 8);
      vreg[0] = *(const f16x8*)(Vtb + (size_t)srow * 2048 + kb + soff * 8);
      kreg[1] = *(const f16x8*)(Kb + (size_t)(kb + srow1) * 1024 + soff * 8);
      vreg[1] = *(const f16x8*)(Vtb + (size_t)srow1 * 2048 + kb + soff * 8);
    }

    #pragma unroll
    for (int nt = 0; nt < 4; nt++) {
      const f16* kp = KsB + (nt * 16 + l16) * 64;
      f16x8 kf0 = *(const f16x8*)(kp + ((quad ^ swz) * 8));
      f16x8 kf1 = *(const f16x8*)(kp + (((4 + quad) ^ swz) * 8));
      f16x4 pf[2];
      f32x4 a0 = {}, a1 = {};
      __builtin_amdgcn_s_setprio(1);
      a0 = __builtin_amdgcn_mfma_f32_16x16x32_f16(kf0, qf[0][0], a0, 0, 0, 0);
      a0 = __builtin_amdgcn_mfma_f32_16x16x32_f16(kf1, qf[0][1], a0, 0, 0, 0);
      a1 = __builtin_amdgcn_mfma_f32_16x16x32_f16(kf0, qf[1][0], a1, 0, 0, 0);
      a1 = __builtin_amdgcn_mfma_f32_16x16x32_f16(kf1, qf[1][1], a1, 0, 0, 0);
      __builtin_amdgcn_s_setprio(0);
      #pragma unroll
      for (int f = 0; f < 2; f++) {
        const f32x4& a = f == 0 ? a0 : a1;
        float e0 = EXP2(a[0]);
        float e1 = EXP2(a[1]);
        float e2 = EXP2(a[2]);
        float e3 = EXP2(a[3]);
        h16x2 lo = __builtin_amdgcn_cvt_pkrtz(e0, e1);
        h16x2 hi = __builtin_amdgcn_cvt_pkrtz(e2, e3);
        f16x2 lo2 = __builtin_bit_cast(f16x2, lo);
        f16x2 hi2 = __builtin_bit_cast(f16x2, hi);
        pf[f] = __builtin_shufflevector(lo2, hi2, 0, 1, 2, 3);
        Osum[f] = __builtin_amdgcn_mfma_f32_16x16x16f16(onesA, pf[f], Osum[f], 0, 0, 0);
      }
      int vchunk = nt * 2 + (quad >> 1);
      __builtin_amdgcn_s_setprio(1);
      #pragma unroll
      for (int mt = 0; mt < 4; mt++) {
        const f16* vp = VsB + (mt * 16 + l16) * 64 + ((vchunk ^ swz) * 8) + (quad & 1) * 4;
        f16x4 vf = *(const f16x4*)vp;
        #pragma unroll
        for (int f = 0; f < 2; f++)
          O[f][mt] = __builtin_amdgcn_mfma_f32_16x16x16f16(vf, pf[f], O[f][mt], 0, 0, 0);
      }
      __builtin_amdgcn_s_setprio(0);
    }
  }

  // store un-normalized partials (transpose through per-wave XOR-swizzled LDS regions)
  #pragma unroll
  for (int f = 0; f < 2; f++) {
    bf16* ob = (f == 0 ? (bf16*)&Ks[0][0] : (bf16*)&Vs[0][0]) + wave * 1024;
    #pragma unroll
    for (int mt = 0; mt < 4; mt++) {
      bf16x4 w;
      #pragma unroll
      for (int i = 0; i < 4; i++) w[i] = (bf16)O[f][mt][i];
      int chunk = mt * 2 + (quad >> 1);
      *(bf16x4*)(ob + l16 * 64 + ((chunk ^ (l16 & 7)) << 3) + (quad & 1) * 4) = w;
    }
  }
  asm volatile("s_waitcnt lgkmcnt(0)" ::: "memory");
  const size_t obase = (size_t)(quarter * 32 + bh) * 2048;
  #pragma unroll
  for (int f = 0; f < 2; f++) {
    const bf16* ob = (f == 0 ? (const bf16*)&Ks[0][0] : (const bf16*)&Vs[0][0]) + wave * 1024;
    int row = lane >> 2, cc = (lane & 3) * 2;
    bf16x8 o0 = *(const bf16x8*)(ob + row * 64 + ((cc ^ (row & 7)) << 3));
    bf16x8 o1 = *(const bf16x8*)(ob + row * 64 + (((cc + 1) ^ (row & 7)) << 3));
    size_t g = (obase + q0 + wave * 32 + f * 16 + row) * 64 + (lane & 3) * 16;
    *(bf16x8*)(Op + g) = o0;
    *(bf16x8*)(Op + g + 8) = o1;
    if (quad == f)
      Rp[obase + q0 + wave * 32 + f * 16 + l16] = Osum[f][0];
  }
}

// ---------------- LN merge: (Pa+Pb[+Pc+Pd]+badd+resid[bf16]) -> LN -> outf? outb? relu? ----------------
__global__ __launch_bounds__(256) void ln_merge(const bf16* __restrict__ Pa,
    const bf16* __restrict__ Pb, const bf16* __restrict__ Pc, const bf16* __restrict__ Pd,
    const float* __restrict__ badd, const bf16* __restrict__ resid,
    const float* __restrict__ gamma, const float* __restrict__ beta,
    float* __restrict__ outf, bf16* __restrict__ outb, int relu)
{
  const int row = blockIdx.x * 4 + (threadIdx.x >> 6);
  const int lane = threadIdx.x & 63;
  const size_t base = (size_t)row * 512;
  const int e0 = lane * 8;
  bf16x8 pa = *(const bf16x8*)(Pa + base + e0);
  bf16x8 pb = *(const bf16x8*)(Pb + base + e0);
  bf16x8 rr = *(const bf16x8*)(resid + base + e0);
  float4 C0 = *(const float4*)(badd + e0);
  float4 C1 = *(const float4*)(badd + e0 + 4);
  float v[8];
  v[0] = (float)pa[0] + (float)pb[0] + (float)rr[0] + C0.x;
  v[1] = (float)pa[1] + (float)pb[1] + (float)rr[1] + C0.y;
  v[2] = (float)pa[2] + (float)pb[2] + (float)rr[2] + C0.z;
  v[3] = (float)pa[3] + (float)pb[3] + (float)rr[3] + C0.w;
  v[4] = (float)pa[4] + (float)pb[4] + (float)rr[4] + C1.x;
  v[5] = (float)pa[5] + (float)pb[5] + (float)rr[5] + C1.y;
  v[6] = (float)pa[6] + (float)pb[6] + (float)rr[6] + C1.z;
  v[7] = (float)pa[7] + (float)pb[7] + (float)rr[7] + C1.w;
  if (Pc) {
    bf16x8 pc = *(const bf16x8*)(Pc + base + e0);
    bf16x8 pd = *(const bf16x8*)(Pd + base + e0);
    #pragma unroll
    for (int i = 0; i < 8; i++) v[i] += (float)pc[i] + (float)pd[i];
  }
  float s = 0.f;
  #pragma unroll
  for (int i = 0; i < 8; i++) s += v[i];
  #pragma unroll
  for (int m = 1; m < 64; m <<= 1) s += __shfl_xor(s, m, 64);
  float mu = s * (1.f / 512.f);
  float d[8], q = 0.f;
  #pragma unroll
  for (int i = 0; i < 8; i++) { d[i] = v[i] - mu; q += d[i] * d[i]; }
  #pragma unroll
  for (int m = 1; m < 64; m <<= 1) q += __shfl_xor(q, m, 64);
  float rsn = rsqrtf(q * (1.f / 512.f) + 1e-5f);
  float4 g0 = *(const float4*)(gamma + e0);
  float4 g1 = *(const float4*)(gamma + e0 + 4);
  float4 b0 = *(const float4*)(beta + e0);
  float4 b1 = *(const float4*)(beta + e0 + 4);
  float y[8];
  y[0] = d[0] * rsn * g0.x + b0.x; y[1] = d[1] * rsn * g0.y + b0.y;
  y[2] = d[2] * rsn * g0.z + b0.z; y[3] = d[3] * rsn * g0.w + b0.w;
  y[4] = d[4] * rsn * g1.x + b1.x; y[5] = d[5] * rsn * g1.y + b1.y;
  y[6] = d[6] * rsn * g1.z + b1.z; y[7] = d[7] * rsn * g1.w + b1.w;
  if (relu) {
    #pragma unroll
    for (int i = 0; i < 8; i++) y[i] = fmaxf(y[i], 0.f);
  }
  if (outf) {
    float4 o0 = {y[0], y[1], y[2], y[3]}, o1 = {y[4], y[5], y[6], y[7]};
    *(float4*)(outf + base + e0) = o0;
    *(float4*)(outf + base + e0 + 4) = o1;
  }
  if (outb) {
    bf16x8 ob;
    #pragma unroll
    for (int i = 0; i < 8; i++) ob[i] = (bf16)y[i];
    *(bf16x8*)(outb + base + e0) = ob;
  }
}

extern "C" void kernel_launch(void* const* d_in, const int* in_sizes, int n_in,
                              void* d_out, int out_size, void* d_ws, size_t ws_size,
                              hipStream_t stream)
{
  const int*   x    = (const int*)  d_in[0];
  const float* emb  = (const float*)d_in[1];
  const float* WfQ  = (const float*)d_in[2];
  const float* bfQv = (const float*)d_in[3];
  const float* WfK  = (const float*)d_in[4];
  const float* bfKv = (const float*)d_in[5];
  const float* WfV  = (const float*)d_in[6];
  const float* bfVv = (const float*)d_in[7];
  const float* WQ   = (const float*)d_in[8];
  const float* bQ   = (const float*)d_in[9];
  const float* WK   = (const float*)d_in[10];
  const float* bK   = (const float*)d_in[11];
  const float* WV   = (const float*)d_in[12];
  const float* bV   = (const float*)d_in[13];
  const float* Wo   = (const float*)d_in[14];
  const float* bo   = (const float*)d_in[15];
  const float* W1   = (const float*)d_in[16];
  const float* b1   = (const float*)d_in[17];
  const float* W2   = (const float*)d_in[18];
  const float* b2   = (const float*)d_in[19];
  const float* gamma= (const float*)d_in[20];
  const float* beta = (const float*)d_in[21];
  float* out = (float*)d_out;

  char* ws = (char*)d_ws;
  const size_t MB = 1024ull * 1024;
  bf16*  bz   = (bf16*) (ws);              // 0-8: z bf16, then a bf16
  f16*   qkh  = (f16*)  (ws + 8 * MB);     // 8-24 (dead after flash)
  f16*   Vt   = (f16*)  (ws + 24 * MB);    // 24-32 (dead after flash)
  bf16*  Op   = (bf16*) (ws + 32 * MB);    // 32-64: flash O partials x4 (live through gemm_wo)
  float* Rp   = (float*)(ws + 64 * MB);    // 64-65: row sums x4 (live through gemm_wo)
  bf16*  PaW  = (bf16*) (ws + 8 * MB);     // Wo partials in dead qkh region (must NOT alias Op!)
  bf16*  PbW  = (bf16*) (ws + 16 * MB);
  bf16*  ffn1 = (bf16*) (ws + 8 * MB);     // 8-40 (PaW/PbW dead after ln_merge; Op dead too)
  bf16*  Pa2  = (bf16*) (ws + 40 * MB);    // FFN2 partials 40-48-56-64-72 (Rp dead by then)
  bf16*  Pb2  = (bf16*) (ws + 48 * MB);
  bf16*  Pc2  = (bf16*) (ws + 56 * MB);
  bf16*  Pd2  = (bf16*) (ws + 64 * MB);
  char* wp = ws + 74 * MB;
  bf16* wfqp = (bf16*)(wp);
  bf16* wfkp = (bf16*)(wp + 512 * 1024);
  bf16* wfvp = (bf16*)(wp + 1024 * 1024);
  bf16* wqt  = (bf16*)(wp + 1536 * 1024);
  bf16* wkt  = (bf16*)(wp + 2048 * 1024);
  bf16* wvt  = (bf16*)(wp + 2560 * 1024);
  bf16* wc   = (bf16*)(wp + 3072 * 1024);
  bf16* wot  = (bf16*)(wp + 4608 * 1024);
  bf16* w1t  = (bf16*)(wp + 5120 * 1024);
  bf16* w2t  = (bf16*)(wp + 7168 * 1024);
  float* bc  = (float*)(wp + 9216 * 1024);

  conv_t<<<dim3(384, 10), 256, 0, stream>>>(Wo, W1, W2, WQ, WK, WV, WfQ, WfK, WfV,
                                            bfQv, bfKv, bfVv, bQ, bK, bV,
                                            wot, w1t, w2t, wqt, wkt, wvt,
                                            wfqp, wfkp, wfvp, bc);
  gemm_comb<<<dim3(4, 8, 3), 256, 0, stream>>>(wqt, wkt, wvt, wfqp, wfkp, wfvp, wc);

  embed_pe<<<8192, 256, 0, stream>>>(x, emb, bz);

  gemm_qkv<<<dim3(64, 12), 256, 0, stream>>>(bz, wc, bc, qkh, Vt);
  flash_attn<<<dim3(16, 16, 4), 256, 0, stream>>>(qkh, Vt, Op, Rp, 0);
  flash_attn<<<dim3(16, 16, 4), 256, 0, stream>>>(qkh, Vt, Op, Rp, 16);

  // Wo GEMM with fused 4-way partial merge (reads Op/Rp; writes PaW/PbW in dead qkh region)
  gemm_wo<<<dim3(64, 4, 2), 256, 0, stream>>>(Op, Rp, wot, PaW, PbW);
  ln_merge<<<2048, 256, 0, stream>>>(PaW, PbW, nullptr, nullptr, bo, bz, gamma, beta,
                                     nullptr, bz, 0);
  gemm_bt<<<dim3(64, 16), 256, 0, stream>>>(bz, w1t, b1, ffn1, 8192, 2048, 512, 1);
  gemm_part<<<dim3(64, 4, 4), 256, 0, stream>>>(ffn1, w2t, Pa2, Pb2, Pc2, Pd2, 512, 2048, 512);
  ln_merge<<<2048, 256, 0, stream>>>(Pa2, Pb2, Pc2, Pd2, b2, bz, gamma, beta, out, nullptr, 1);
}

// Round 10
// 321.102 us; speedup vs baseline: 1.0371x; 1.0371x over previous
//
#include <hip/hip_runtime.h>
#include <math.h>

typedef __bf16 bf16;
typedef __bf16 bf16x8 __attribute__((ext_vector_type(8)));
typedef __bf16 bf16x4 __attribute__((ext_vector_type(4)));
typedef _Float16 f16;
typedef _Float16 f16x8 __attribute__((ext_vector_type(8)));
typedef _Float16 f16x4 __attribute__((ext_vector_type(4)));
typedef _Float16 f16x2 __attribute__((ext_vector_type(2)));
typedef __fp16 h16x2 __attribute__((ext_vector_type(2)));
typedef float f32x4 __attribute__((ext_vector_type(4)));
typedef unsigned int u32;

#define S_LEN 2048
#define QSCALE 0.18033688011112042f   // (1/8)*log2(e), folded into Q weights+bias

#if __has_builtin(__builtin_amdgcn_exp2f)
#define EXP2(x) __builtin_amdgcn_exp2f(x)   // raw v_exp_f32, no OCML denormal guard
#else
#define EXP2(x) exp2f(x)
#endif

__device__ __forceinline__ void gload_lds16(const void* g, void* l) {
  __builtin_amdgcn_global_load_lds((const __attribute__((address_space(1))) u32*)g,
                                   (__attribute__((address_space(3))) u32*)l, 16, 0, 0);
}

// ---------------- embedding + sinusoidal PE (bf16 out only) ----------------
__global__ __launch_bounds__(256) void embed_pe(const int* __restrict__ x,
    const float* __restrict__ emb, bf16* __restrict__ zb)
{
  const int row = blockIdx.x;
  const int s = row & (S_LEN - 1);
  const int tok = x[row];
  const float* e = emb + (size_t)tok * 512;
  bf16* zbr = zb + (size_t)row * 512;
  for (int i = threadIdx.x; i < 512; i += 256) {
    float invf = __expf((float)i * (-9.210340371976184f / 512.0f));
    float ang = (float)s * invf;
    float pe = (i & 1) ? __cosf(ang) : __sinf(ang);
    zbr[i] = (bf16)(e[i] + pe);
  }
}

// ---------------- weight prep: bias (y=9) + copies (y=6..8) + LDS-tiled transposes (y=0..5) ----------------
__global__ __launch_bounds__(256) void conv_t(
    const float* __restrict__ Wo, const float* __restrict__ W1, const float* __restrict__ W2,
    const float* __restrict__ WQ, const float* __restrict__ WK, const float* __restrict__ WV,
    const float* __restrict__ WfQ, const float* __restrict__ WfK, const float* __restrict__ WfV,
    const float* __restrict__ bfQ, const float* __restrict__ bfK, const float* __restrict__ bfV,
    const float* __restrict__ bQ, const float* __restrict__ bK, const float* __restrict__ bV,
    bf16* __restrict__ wot, bf16* __restrict__ w1t, bf16* __restrict__ w2t,
    bf16* __restrict__ wqt, bf16* __restrict__ wkt, bf16* __restrict__ wvt,
    bf16* __restrict__ wfqp, bf16* __restrict__ wfkp, bf16* __restrict__ wfvp,
    float* __restrict__ bc)
{
  __shared__ float T[64][65];
  const int y = blockIdx.y, x = blockIdx.x;
  if (y == 9) {                                   // combined bias, x < 384
    int n = x * 4 + ((int)threadIdx.x >> 6);
    int lane = threadIdx.x & 63;
    int z = n >> 9, hk = n & 511, h = hk >> 6, k = hk & 63;
    const float* bf = z == 0 ? bfQ : (z == 1 ? bfK : bfV);
    const float* W  = z == 0 ? WQ  : (z == 1 ? WK  : WV);
    const float* bH = z == 0 ? bQ  : (z == 1 ? bK  : bV);
    float s = 0.f;
    for (int e = lane; e < 512; e += 64)
      s += bf[e] * W[((size_t)h * 512 + e) * 64 + k];
    #pragma unroll
    for (int m = 1; m < 64; m <<= 1) s += __shfl_xor(s, m, 64);
    if (lane == 0) {
      float v = s + bH[h * 64 + k];
      if (z == 0) v *= QSCALE;
      bc[n] = v;
    }
    return;
  }
  if (y >= 6) {
    if (x >= 256) return;
    int g = x * 256 + threadIdx.x;               // 65536 float4 per tensor
    const float* in = y == 6 ? WfQ : (y == 7 ? WfK : WfV);
    bf16* outp = y == 6 ? wfqp : (y == 7 ? wfkp : wfvp);
    float4 v = *(const float4*)(in + (size_t)g * 4);
    bf16x4 o = {(bf16)v.x, (bf16)v.y, (bf16)v.z, (bf16)v.w};
    *(bf16x4*)(outp + (size_t)g * 4) = o;
    return;
  }
  const int tx = threadIdx.x & 63, ty = threadIdx.x >> 6;
  const float* src; bf16* dst;
  int src_cols, dst_cols; float scale = 1.f;
  if (y == 0) {
    if (x >= 64) return;
    int kt = x & 7, nt = x >> 3;
    src = Wo + (size_t)(kt * 64) * 512 + nt * 64; src_cols = 512;
    dst = wot + (size_t)(nt * 64) * 512 + kt * 64; dst_cols = 512;
  } else if (y == 1) {
    if (x >= 256) return;
    int kt = x & 7, nt = x >> 3;
    src = W1 + (size_t)(kt * 64) * 2048 + nt * 64; src_cols = 2048;
    dst = w1t + (size_t)(nt * 64) * 512 + kt * 64; dst_cols = 512;
  } else if (y == 2) {
    if (x >= 256) return;
    int kt = x & 31, nt = x >> 5;
    src = W2 + (size_t)(kt * 64) * 512 + nt * 64; src_cols = 512;
    dst = w2t + (size_t)(nt * 64) * 2048 + kt * 64; dst_cols = 2048;
  } else {
    if (x >= 64) return;
    const float* W = y == 3 ? WQ : (y == 4 ? WK : WV);
    bf16* o = y == 3 ? wqt : (y == 4 ? wkt : wvt);
    if (y == 3) scale = QSCALE;
    int h = x >> 3, rt = x & 7;
    src = W + (size_t)(h * 512 + rt * 64) * 64; src_cols = 64;
    dst = o + (size_t)(h * 64) * 512 + rt * 64; dst_cols = 512;
  }
  #pragma unroll
  for (int i = 0; i < 16; i++) {
    int rr = i * 4 + ty;
    T[rr][tx] = src[(size_t)rr * src_cols + tx];
  }
  __syncthreads();
  #pragma unroll
  for (int i = 0; i < 16; i++) {
    int rr = i * 4 + ty;
    dst[(size_t)rr * dst_cols + tx] = (bf16)(T[tx][rr] * scale);
  }
}

// ---------------- weight-combine GEMMs (3 in one launch, 128x64 tiles) ----------------
__global__ __launch_bounds__(256) void gemm_comb(
    const bf16* __restrict__ wqt, const bf16* __restrict__ wkt, const bf16* __restrict__ wvt,
    const bf16* __restrict__ wfqp, const bf16* __restrict__ wfkp, const bf16* __restrict__ wfvp,
    bf16* __restrict__ wc)
{
  __shared__ bf16 As[128 * 32];
  __shared__ bf16 Bs[64 * 32];
  const int z = blockIdx.z;
  const bf16* A  = z == 0 ? wqt : (z == 1 ? wkt : wvt);
  const bf16* Bt = z == 0 ? wfqp : (z == 1 ? wfkp : wfvp);
  bf16* outb = wc + (size_t)z * 262144;
  const int tid = threadIdx.x;
  const int wave = tid >> 6, lane = tid & 63, quad = lane >> 4, l16 = lane & 15;
  const int row0 = blockIdx.x * 128, col0 = blockIdx.y * 64;
  const int wm = wave >> 1, wn = wave & 1;
  f32x4 acc[4][2] = {};

  for (int kk = 0; kk < 512; kk += 32) {
    __syncthreads();
    #pragma unroll
    for (int r = 0; r < 2; r++) {
      int c = r * 256 + tid;
      gload_lds16(A + (size_t)(row0 + (c >> 2)) * 512 + kk + (c & 3) * 8, As + c * 8);
    }
    gload_lds16(Bt + (size_t)(col0 + (tid >> 2)) * 512 + kk + (tid & 3) * 8, Bs + tid * 8);
    __syncthreads();
    bf16x8 af[4], bfr[2];
    #pragma unroll
    for (int i = 0; i < 4; i++)
      af[i] = *(const bf16x8*)(As + (wm * 64 + i * 16 + l16) * 32 + quad * 8);
    #pragma unroll
    for (int i = 0; i < 2; i++)
      bfr[i] = *(const bf16x8*)(Bs + (wn * 32 + i * 16 + l16) * 32 + quad * 8);
    #pragma unroll
    for (int mt = 0; mt < 4; mt++)
      #pragma unroll
      for (int nt = 0; nt < 2; nt++)
        acc[mt][nt] = __builtin_amdgcn_mfma_f32_16x16x32_bf16(af[mt], bfr[nt], acc[mt][nt], 0, 0, 0);
  }
  #pragma unroll
  for (int nt = 0; nt < 2; nt++) {
    int col = col0 + wn * 32 + nt * 16 + l16;
    #pragma unroll
    for (int mt = 0; mt < 4; mt++) {
      int rowb = row0 + wm * 64 + mt * 16 + quad * 4;
      #pragma unroll
      for (int i = 0; i < 4; i++)
        outb[(size_t)(rowb + i) * 512 + col] = (bf16)acc[mt][nt][i];
    }
  }
}

// ======== dbuf reg-prefetch GEMM core (128x128 tile, BK=32, 1 barrier/iter) ========
#define GEMM_CORE(A_, Bt_, K_, KK0_, ITERS_)                                            \
  bf16x8 ar0, ar1, br0, br1;                                                            \
  const int c0 = tid, c1 = 256 + tid;                                                   \
  const size_t aoff0 = (size_t)(row0 + (c0 >> 2)) * (K_) + (c0 & 3) * 8;                \
  const size_t aoff1 = (size_t)(row0 + (c1 >> 2)) * (K_) + (c1 & 3) * 8;                \
  const size_t boff0 = (size_t)(col0 + (c0 >> 2)) * (K_) + (c0 & 3) * 8;                \
  const size_t boff1 = (size_t)(col0 + (c1 >> 2)) * (K_) + (c1 & 3) * 8;                \
  ar0 = *(const bf16x8*)((A_) + aoff0 + (KK0_));                                        \
  ar1 = *(const bf16x8*)((A_) + aoff1 + (KK0_));                                        \
  br0 = *(const bf16x8*)((Bt_) + boff0 + (KK0_));                                       \
  br1 = *(const bf16x8*)((Bt_) + boff1 + (KK0_));                                       \
  for (int it = 0; it < (ITERS_); it++) {                                               \
    bf16* AsB = As[it & 1];                                                             \
    bf16* BsB = Bs[it & 1];                                                             \
    *(bf16x8*)(AsB + c0 * 8) = ar0;                                                     \
    *(bf16x8*)(AsB + c1 * 8) = ar1;                                                     \
    *(bf16x8*)(BsB + c0 * 8) = br0;                                                     \
    *(bf16x8*)(BsB + c1 * 8) = br1;                                                     \
    __syncthreads();                                                                    \
    if (it + 1 < (ITERS_)) {                                                            \
      int kk = (KK0_) + (it + 1) * 32;                                                  \
      ar0 = *(const bf16x8*)((A_) + aoff0 + kk);                                        \
      ar1 = *(const bf16x8*)((A_) + aoff1 + kk);                                        \
      br0 = *(const bf16x8*)((Bt_) + boff0 + kk);                                      \
      br1 = *(const bf16x8*)((Bt_) + boff1 + kk);                                      \
    }                                                                                   \
    bf16x8 af[4], bfr[4];                                                               \
    _Pragma("unroll")                                                                   \
    for (int i = 0; i < 4; i++)                                                         \
      af[i] = *(const bf16x8*)(AsB + (wm * 64 + i * 16 + l16) * 32 + quad * 8);         \
    _Pragma("unroll")                                                                   \
    for (int i = 0; i < 4; i++)                                                         \
      bfr[i] = *(const bf16x8*)(BsB + (wn * 64 + i * 16 + l16) * 32 + quad * 8);        \
    _Pragma("unroll")                                                                   \
    for (int mt = 0; mt < 4; mt++)                                                      \
      _Pragma("unroll")                                                                 \
      for (int nt = 0; nt < 4; nt++)                                                    \
        acc[mt][nt] = __builtin_amdgcn_mfma_f32_16x16x32_bf16(af[mt], bfr[nt], acc[mt][nt], 0, 0, 0); \
  }

// ---------------- GEMM 128x128 (bias, optional relu, bf16 out; FFN1) ----------------
__global__ __launch_bounds__(256) void gemm_bt(
    const bf16* __restrict__ A, const bf16* __restrict__ Bt,
    const float* __restrict__ bias, bf16* __restrict__ outb,
    int M, int N, int K, int relu)
{
  __shared__ bf16 As[2][4096];
  __shared__ bf16 Bs[2][4096];
  const int tid = threadIdx.x;
  const int wave = tid >> 6, lane = tid & 63, quad = lane >> 4, l16 = lane & 15;
  const int row0 = blockIdx.x * 128, col0 = blockIdx.y * 128;
  const int wm = wave >> 1, wn = wave & 1;
  f32x4 acc[4][4] = {};
  GEMM_CORE(A, Bt, K, 0, K / 32)

  #pragma unroll
  for (int nt = 0; nt < 4; nt++) {
    int col = col0 + wn * 64 + nt * 16 + l16;
    float bv = bias[col];
    #pragma unroll
    for (int mt = 0; mt < 4; mt++) {
      int rowb = row0 + wm * 64 + mt * 16 + quad * 4;
      #pragma unroll
      for (int i = 0; i < 4; i++) {
        float v = acc[mt][nt][i] + bv;
        if (relu) v = fmaxf(v, 0.f);
        outb[(size_t)(rowb + i) * N + col] = (bf16)v;
      }
    }
  }
}

// ---------------- QKV GEMM: N=1536, qk f16[row][1024] + Vt f16[bh][dv][2048] ----------------
// V-block epilogue stages through XOR-swizzled LDS so Vt writes are 256B-contiguous along s
// (old path: 8B scatter at 4KB stride). Sole change vs the 315us R8 baseline (clean A/B).
__global__ __launch_bounds__(256) void gemm_qkv(
    const bf16* __restrict__ A, const bf16* __restrict__ Bt,
    const float* __restrict__ bias, f16* __restrict__ qk, f16* __restrict__ Vt)
{
  __shared__ char ldsbuf[32768];
  bf16 (*As)[4096] = (bf16(*)[4096])ldsbuf;
  bf16 (*Bs)[4096] = (bf16(*)[4096])(ldsbuf + 16384);
  const int tid = threadIdx.x;
  const int wave = tid >> 6, lane = tid & 63, quad = lane >> 4, l16 = lane & 15;
  const int row0 = blockIdx.x * 128, col0 = blockIdx.y * 128;
  const int wm = wave >> 1, wn = wave & 1;
  f32x4 acc[4][4] = {};
  GEMM_CORE(A, Bt, 512, 0, 16)

  if (col0 >= 1024) {
    // V path: transpose 128 cols x 128 rows through LDS, coalesced Vt writes
    f16* Vst = (f16*)ldsbuf;                     // [128 cols][128 rows], chunk-XOR swizzled
    const int h0 = (col0 - 1024) >> 6;
    const int b = row0 >> 11, s0 = row0 & 2047;
    __syncthreads();                             // main-loop LDS reads complete
    #pragma unroll
    for (int nt = 0; nt < 4; nt++) {
      int c = wn * 64 + nt * 16 + l16;
      float bv = bias[col0 + c];
      #pragma unroll
      for (int mt = 0; mt < 4; mt++) {
        int chunk = wm * 16 + mt * 4 + quad;     // r = chunk*4 + i
        f16x4 vv;
        #pragma unroll
        for (int i = 0; i < 4; i++) vv[i] = (f16)(acc[mt][nt][i] + bv);
        *(f16x4*)(Vst + c * 128 + ((chunk ^ ((c & 7) << 2)) * 4)) = vv;
      }
    }
    __syncthreads();
    #pragma unroll
    for (int p = 0; p < 16; p++) {
      int c = p * 8 + (tid >> 5);
      int ch = tid & 31;
      f16x4 vv = *(const f16x4*)(Vst + c * 128 + ((ch ^ ((c & 7) << 2)) * 4));
      int h = h0 + (c >> 6), dv = c & 63;
      *(f16x4*)(Vt + ((size_t)((b * 8 + h) * 64 + dv)) * 2048 + s0 + ch * 4) = vv;
    }
    return;
  }

  #pragma unroll
  for (int nt = 0; nt < 4; nt++) {
    int col = col0 + wn * 64 + nt * 16 + l16;
    float bv = bias[col];
    #pragma unroll
    for (int mt = 0; mt < 4; mt++) {
      int rowb = row0 + wm * 64 + mt * 16 + quad * 4;
      #pragma unroll
      for (int i = 0; i < 4; i++)
        qk[(size_t)(rowb + i) * 1024 + col] = (f16)(acc[mt][nt][i] + bv);
    }
  }
}

// ---------------- split-K partial GEMM -> bf16 partials (FFN2, 2-way) ----------------
__global__ __launch_bounds__(256) void gemm_part(
    const bf16* __restrict__ A, const bf16* __restrict__ Bt,
    bf16* __restrict__ Pa, bf16* __restrict__ Pb, int N, int K, int Kh)
{
  __shared__ bf16 As[2][4096];
  __shared__ bf16 Bs[2][4096];
  const int tid = threadIdx.x;
  const int wave = tid >> 6, lane = tid & 63, quad = lane >> 4, l16 = lane & 15;
  const int row0 = blockIdx.x * 128, col0 = blockIdx.y * 128;
  const int wm = wave >> 1, wn = wave & 1;
  const int kk0 = blockIdx.z * Kh;
  bf16* P = blockIdx.z ? Pb : Pa;
  f32x4 acc[4][4] = {};
  GEMM_CORE(A, Bt, K, kk0, Kh / 32)

  #pragma unroll
  for (int nt = 0; nt < 4; nt++) {
    int col = col0 + wn * 64 + nt * 16 + l16;
    #pragma unroll
    for (int mt = 0; mt < 4; mt++) {
      int rowb = row0 + wm * 64 + mt * 16 + quad * 4;
      #pragma unroll
      for (int i = 0; i < 4; i++)
        P[(size_t)(rowb + i) * N + col] = (bf16)acc[mt][nt][i];
    }
  }
}

// ---------------- Wo GEMM with fused attention-partial merge ----------------
__global__ __launch_bounds__(256) void gemm_wo(
    const bf16* __restrict__ Op, const float* __restrict__ Rp,
    const bf16* __restrict__ Bt, bf16* __restrict__ Pa, bf16* __restrict__ Pb)
{
  __shared__ bf16 As[2][4096];
  __shared__ bf16 Bs[2][4096];
  const int tid = threadIdx.x;
  const int wave = tid >> 6, lane = tid & 63, quad = lane >> 4, l16 = lane & 15;
  const int row0 = blockIdx.x * 128, col0 = blockIdx.y * 128;
  const int wm = wave >> 1, wn = wave & 1;
  const int kk0 = blockIdx.z * 256;
  bf16* P = blockIdx.z ? Pb : Pa;
  f32x4 acc[4][4] = {};

  const int c0 = tid, c1 = 256 + tid;
  const int r0 = row0 + (c0 >> 2), r1 = r0 + 64;
  const int b0 = r0 >> 11, s0 = r0 & 2047;
  const int b1 = r1 >> 11, s1 = r1 & 2047;
  const int ccol = (c0 & 3) * 8;
  const int h0 = kk0 >> 6;
  const size_t boff0 = (size_t)(col0 + (c0 >> 2)) * 512 + ccol;
  const size_t boff1 = (size_t)(col0 + 64 + (c0 >> 2)) * 512 + ccol;

  float inv0[4], inv1[4];
  #pragma unroll
  for (int hh = 0; hh < 4; hh++) {
    int hg = h0 + hh;
    int ra = (b0 * 8 + hg) * 2048 + s0;
    float r = (Rp[ra] + Rp[65536 + ra]) + (Rp[131072 + ra] + Rp[196608 + ra]);
    inv0[hh] = 1.f / r;
    int rb = (b1 * 8 + hg) * 2048 + s1;
    r = (Rp[rb] + Rp[65536 + rb]) + (Rp[131072 + rb] + Rp[196608 + rb]);
    inv1[hh] = 1.f / r;
  }

  bf16x8 p0q[4], p1q[4], br0, br1;
  {
    int hg = h0, dv = ccol;
    size_t ia0 = ((size_t)(b0 * 8 + hg) * 2048 + s0) * 64 + dv;
    size_t ia1 = ((size_t)(b1 * 8 + hg) * 2048 + s1) * 64 + dv;
    #pragma unroll
    for (int q = 0; q < 4; q++) {
      p0q[q] = *(const bf16x8*)(Op + q * 4194304ull + ia0);
      p1q[q] = *(const bf16x8*)(Op + q * 4194304ull + ia1);
    }
    br0 = *(const bf16x8*)(Bt + boff0 + kk0);
    br1 = *(const bf16x8*)(Bt + boff1 + kk0);
  }

  for (int it = 0; it < 8; it++) {
    bf16* AsB = As[it & 1];
    bf16* BsB = Bs[it & 1];
    const float iv0 = inv0[it >> 1], iv1 = inv1[it >> 1];
    bf16x8 a0v, a1v;
    #pragma unroll
    for (int i = 0; i < 8; i++) {
      float v0 = ((float)p0q[0][i] + (float)p0q[1][i]) + ((float)p0q[2][i] + (float)p0q[3][i]);
      float v1 = ((float)p1q[0][i] + (float)p1q[1][i]) + ((float)p1q[2][i] + (float)p1q[3][i]);
      a0v[i] = (bf16)(v0 * iv0);
      a1v[i] = (bf16)(v1 * iv1);
    }
    *(bf16x8*)(AsB + c0 * 8) = a0v;
    *(bf16x8*)(AsB + c1 * 8) = a1v;
    *(bf16x8*)(BsB + c0 * 8) = br0;
    *(bf16x8*)(BsB + c1 * 8) = br1;
    __syncthreads();
    if (it < 7) {
      int itn = it + 1;
      int kk = kk0 + itn * 32;
      int hg = h0 + (itn >> 1);
      int dv = (itn & 1) * 32 + ccol;
      size_t ia0 = ((size_t)(b0 * 8 + hg) * 2048 + s0) * 64 + dv;
      size_t ia1 = ((size_t)(b1 * 8 + hg) * 2048 + s1) * 64 + dv;
      #pragma unroll
      for (int q = 0; q < 4; q++) {
        p0q[q] = *(const bf16x8*)(Op + q * 4194304ull + ia0);
        p1q[q] = *(const bf16x8*)(Op + q * 4194304ull + ia1);
      }
      br0 = *(const bf16x8*)(Bt + boff0 + kk);
      br1 = *(const bf16x8*)(Bt + boff1 + kk);
    }
    bf16x8 af[4], bfr[4];
    #pragma unroll
    for (int i = 0; i < 4; i++)
      af[i] = *(const bf16x8*)(AsB + (wm * 64 + i * 16 + l16) * 32 + quad * 8);
    #pragma unroll
    for (int i = 0; i < 4; i++)
      bfr[i] = *(const bf16x8*)(BsB + (wn * 64 + i * 16 + l16) * 32 + quad * 8);
    #pragma unroll
    for (int mt = 0; mt < 4; mt++)
      #pragma unroll
      for (int nt = 0; nt < 4; nt++)
        acc[mt][nt] = __builtin_amdgcn_mfma_f32_16x16x32_bf16(af[mt], bfr[nt], acc[mt][nt], 0, 0, 0);
  }

  #pragma unroll
  for (int nt = 0; nt < 4; nt++) {
    int col = col0 + wn * 64 + nt * 16 + l16;
    #pragma unroll
    for (int mt = 0; mt < 4; mt++) {
      int rowb = row0 + wm * 64 + mt * 16 + quad * 4;
      #pragma unroll
      for (int i = 0; i < 4; i++)
        P[(size_t)(rowb + i) * 512 + col] = (bf16)acc[mt][nt][i];
    }
  }
}

// ---------------- flash attention: 32 q/wave, split-K 4, dbuf, rsum via ones-MFMA ----------------
// qk: [8192][1024] f16; Vt: [32 bh][64 dv][2048 s] f16. Grid (16 qtile, 32 bh, 4 quarter).
__global__ __launch_bounds__(256, 2) void flash_attn(
    const f16* __restrict__ qk, const f16* __restrict__ Vt,
    bf16* __restrict__ Op, float* __restrict__ Rp)
{
  __shared__ f16 Ks[2][4096];   // [key][dk], 16B chunks XOR-swizzled by row&7
  __shared__ f16 Vs[2][4096];   // [dv][key], same swizzle
  const int bh = blockIdx.y, b = bh >> 3, h = bh & 7;
  const int q0 = blockIdx.x * 128;
  const int quarter = blockIdx.z;
  const int tid = threadIdx.x;
  const int wave = tid >> 6, lane = tid & 63, quad = lane >> 4, l16 = lane & 15;

  const f16* Qb = qk + ((size_t)b * S_LEN) * 1024 + h * 64;
  const f16* Kb = Qb + 512;
  const f16* Vtb = Vt + ((size_t)bh * 64) * 2048;
  const int key0 = quarter * 512;

  f16x8 qf[2][2];
  #pragma unroll
  for (int f = 0; f < 2; f++) {
    int qrow = q0 + wave * 32 + f * 16 + l16;
    #pragma unroll
    for (int kh = 0; kh < 2; kh++)
      qf[f][kh] = *(const f16x8*)(Qb + (size_t)qrow * 1024 + kh * 32 + quad * 8);
  }

  f32x4 O[2][4] = {};            // [f][mt]: O^T row=dv, col=q
  f32x4 Osum[2] = {};            // rsum accumulator via ones-MFMA
  const f16x4 onesA = {(f16)1.f, (f16)1.f, (f16)1.f, (f16)1.f};
  const int swz = l16 & 7;

  f16x8 kreg[2], vreg[2];
  const int srow = tid >> 3, soff = tid & 7;
  const int srow1 = srow + 32;

  {
    int kb = key0;
    kreg[0] = *(const f16x8*)(Kb + (size_t)(kb + srow) * 1024 + soff * 8);
    vreg[0] = *(const f16x8*)(Vtb + (size_t)srow * 2048 + kb + soff * 8);
    kreg[1] = *(const f16x8*)(Kb + (size_t)(kb + srow1) * 1024 + soff * 8);
    vreg[1] = *(const f16x8*)(Vtb + (size_t)srow1 * 2048 + kb + soff * 8);
  }

  for (int c = 0; c < 8; c++) {
    f16* KsB = Ks[c & 1];
    f16* VsB = Vs[c & 1];
    *(f16x8*)(KsB + srow * 64 + ((soff ^ (srow & 7)) * 8)) = kreg[0];
    *(f16x8*)(VsB + srow * 64 + ((soff ^ (srow & 7)) * 8)) = vreg[0];
    *(f16x8*)(KsB + srow1 * 64 + ((soff ^ (srow1 & 7)) * 8)) = kreg[1];
    *(f16x8*)(VsB + srow1 * 64 + ((soff ^ (srow1 & 7)) * 8)) = vreg[1];
    __syncthreads();
    if (c < 7) {
      int kb = key0 + (c + 1) * 64;
      kreg[0] = *(const f16x8*)(Kb + (size_t)(kb + srow) * 1024 + soff * 8);
      vreg[0] = *(const f16x8*)(Vtb + (size_t)srow * 2048 + kb + soff * 8);
      kreg[1] = *(const f16x8*)(Kb + (size_t)(kb + srow1) * 1024 + soff * 8);
      vreg[1] = *(const f16x8*)(Vtb + (size_t)srow1 * 2048 + kb + soff * 8);
    }

    #pragma unroll
    for (int nt = 0; nt < 4; nt++) {
      const f16* kp = KsB + (nt * 16 + l16) * 64;
      f16x8 kf0 = *(const f16x8*)(kp + ((quad ^ swz) * 8));
      f16x8 kf1 = *(const f16x8*)(kp + (((4 + quad) ^ swz) * 8));
      f16x4 pf[2];
      f32x4 a0 = {}, a1 = {};
      __builtin_amdgcn_s_setprio(1);
      a0 = __builtin_amdgcn_mfma_f32_16x16x32_f16(kf0, qf[0][0], a0, 0, 0, 0);
      a0 = __builtin_amdgcn_mfma_f32_16x16x32_f16(kf1, qf[0][1], a0, 0, 0, 0);
      a1 = __builtin_amdgcn_mfma_f32_16x16x32_f16(kf0, qf[1][0], a1, 0, 0, 0);
      a1 = __builtin_amdgcn_mfma_f32_16x16x32_f16(kf1, qf[1][1], a1, 0, 0, 0);
      __builtin_amdgcn_s_setprio(0);
      #pragma unroll
      for (int f = 0; f < 2; f++) {
        const f32x4& a = f == 0 ? a0 : a1;
        float e0 = EXP2(a[0]);
        float e1 = EXP2(a[1]);
        float e2 = EXP2(a[2]);
        float e3 = EXP2(a[3]);
        h16x2 lo = __builtin_amdgcn_cvt_pkrtz(e0, e1);
        h16x2 hi = __builtin_amdgcn_cvt_pkrtz(e2, e3);
        f16x2 lo2 = __builtin_bit_cast(f16x2, lo);
        f16x2 hi2 = __builtin_bit_cast(f16x2, hi);
        pf[f] = __builtin_shufflevector(lo2, hi2, 0, 1, 2, 3);
        Osum[f] = __builtin_amdgcn_mfma_f32_16x16x16f16(onesA, pf[f], Osum[f], 0, 0, 0);
      }
      int vchunk = nt * 2 + (quad >> 1);
      __builtin_amdgcn_s_setprio(1);
      #pragma unroll
      for (int mt = 0; mt < 4; mt++) {
        const f16* vp = VsB + (mt * 16 + l16) * 64 + ((vchunk ^ swz) * 8) + (quad & 1) * 4;
        f16x4 vf = *(const f16x4*)vp;
        #pragma unroll
        for (int f = 0; f < 2; f++)
          O[f][mt] = __builtin_amdgcn_mfma_f32_16x16x16f16(vf, pf[f], O[f][mt], 0, 0, 0);
      }
      __builtin_amdgcn_s_setprio(0);
    }
  }

  // store un-normalized partials (transpose through per-wave XOR-swizzled LDS regions)
  #pragma unroll
  for (int f = 0; f < 2; f++) {
    bf16* ob = (f == 0 ? (bf16*)&Ks[0][0] : (bf16*)&Vs[0][0]) + wave * 1024;
    #pragma unroll
    for (int mt = 0; mt < 4; mt++) {
      bf16x4 w;
      #pragma unroll
      for (int i = 0; i < 4; i++) w[i] = (bf16)O[f][mt][i];
      int chunk = mt * 2 + (quad >> 1);
      *(bf16x4*)(ob + l16 * 64 + ((chunk ^ (l16 & 7)) << 3) + (quad & 1) * 4) = w;
    }
  }
  asm volatile("s_waitcnt lgkmcnt(0)" ::: "memory");
  const size_t obase = (size_t)(quarter * 32 + bh) * 2048;
  #pragma unroll
  for (int f = 0; f < 2; f++) {
    const bf16* ob = (f == 0 ? (const bf16*)&Ks[0][0] : (const bf16*)&Vs[0][0]) + wave * 1024;
    int row = lane >> 2, cc = (lane & 3) * 2;
    bf16x8 o0 = *(const bf16x8*)(ob + row * 64 + ((cc ^ (row & 7)) << 3));
    bf16x8 o1 = *(const bf16x8*)(ob + row * 64 + (((cc + 1) ^ (row & 7)) << 3));
    size_t g = (obase + q0 + wave * 32 + f * 16 + row) * 64 + (lane & 3) * 16;
    *(bf16x8*)(Op + g) = o0;
    *(bf16x8*)(Op + g + 8) = o1;
    if (quad == f)
      Rp[obase + q0 + wave * 32 + f * 16 + l16] = Osum[f][0];
  }
}

// ---------------- LN merge: (Pa+Pb+badd+resid[bf16]) -> LN -> outf? outb? relu? ----------------
__global__ __launch_bounds__(256) void ln_merge(const bf16* __restrict__ Pa,
    const bf16* __restrict__ Pb, const float* __restrict__ badd,
    const bf16* __restrict__ resid, const float* __restrict__ gamma,
    const float* __restrict__ beta, float* __restrict__ outf,
    bf16* __restrict__ outb, int relu)
{
  const int row = blockIdx.x * 4 + (threadIdx.x >> 6);
  const int lane = threadIdx.x & 63;
  const size_t base = (size_t)row * 512;
  const int e0 = lane * 8;
  bf16x8 pa = *(const bf16x8*)(Pa + base + e0);
  bf16x8 pb = *(const bf16x8*)(Pb + base + e0);
  bf16x8 rr = *(const bf16x8*)(resid + base + e0);
  float4 C0 = *(const float4*)(badd + e0);
  float4 C1 = *(const float4*)(badd + e0 + 4);
  float v[8];
  v[0] = (float)pa[0] + (float)pb[0] + (float)rr[0] + C0.x;
  v[1] = (float)pa[1] + (float)pb[1] + (float)rr[1] + C0.y;
  v[2] = (float)pa[2] + (float)pb[2] + (float)rr[2] + C0.z;
  v[3] = (float)pa[3] + (float)pb[3] + (float)rr[3] + C0.w;
  v[4] = (float)pa[4] + (float)pb[4] + (float)rr[4] + C1.x;
  v[5] = (float)pa[5] + (float)pb[5] + (float)rr[5] + C1.y;
  v[6] = (float)pa[6] + (float)pb[6] + (float)rr[6] + C1.z;
  v[7] = (float)pa[7] + (float)pb[7] + (float)rr[7] + C1.w;
  float s = 0.f;
  #pragma unroll
  for (int i = 0; i < 8; i++) s += v[i];
  #pragma unroll
  for (int m = 1; m < 64; m <<= 1) s += __shfl_xor(s, m, 64);
  float mu = s * (1.f / 512.f);
  float d[8], q = 0.f;
  #pragma unroll
  for (int i = 0; i < 8; i++) { d[i] = v[i] - mu; q += d[i] * d[i]; }
  #pragma unroll
  for (int m = 1; m < 64; m <<= 1) q += __shfl_xor(q, m, 64);
  float rsn = rsqrtf(q * (1.f / 512.f) + 1e-5f);
  float4 g0 = *(const float4*)(gamma + e0);
  float4 g1 = *(const float4*)(gamma + e0 + 4);
  float4 b0 = *(const float4*)(beta + e0);
  float4 b1 = *(const float4*)(beta + e0 + 4);
  float y[8];
  y[0] = d[0] * rsn * g0.x + b0.x; y[1] = d[1] * rsn * g0.y + b0.y;
  y[2] = d[2] * rsn * g0.z + b0.z; y[3] = d[3] * rsn * g0.w + b0.w;
  y[4] = d[4] * rsn * g1.x + b1.x; y[5] = d[5] * rsn * g1.y + b1.y;
  y[6] = d[6] * rsn * g1.z + b1.z; y[7] = d[7] * rsn * g1.w + b1.w;
  if (relu) {
    #pragma unroll
    for (int i = 0; i < 8; i++) y[i] = fmaxf(y[i], 0.f);
  }
  if (outf) {
    float4 o0 = {y[0], y[1], y[2], y[3]}, o1 = {y[4], y[5], y[6], y[7]};
    *(float4*)(outf + base + e0) = o0;
    *(float4*)(outf + base + e0 + 4) = o1;
  }
  if (outb) {
    bf16x8 ob;
    #pragma unroll
    for (int i = 0; i < 8; i++) ob[i] = (bf16)y[i];
    *(bf16x8*)(outb + base + e0) = ob;
  }
}

extern "C" void kernel_launch(void* const* d_in, const int* in_sizes, int n_in,
                              void* d_out, int out_size, void* d_ws, size_t ws_size,
                              hipStream_t stream)
{
  const int*   x    = (const int*)  d_in[0];
  const float* emb  = (const float*)d_in[1];
  const float* WfQ  = (const float*)d_in[2];
  const float* bfQv = (const float*)d_in[3];
  const float* WfK  = (const float*)d_in[4];
  const float* bfKv = (const float*)d_in[5];
  const float* WfV  = (const float*)d_in[6];
  const float* bfVv = (const float*)d_in[7];
  const float* WQ   = (const float*)d_in[8];
  const float* bQ   = (const float*)d_in[9];
  const float* WK   = (const float*)d_in[10];
  const float* bK   = (const float*)d_in[11];
  const float* WV   = (const float*)d_in[12];
  const float* bV   = (const float*)d_in[13];
  const float* Wo   = (const float*)d_in[14];
  const float* bo   = (const float*)d_in[15];
  const float* W1   = (const float*)d_in[16];
  const float* b1   = (const float*)d_in[17];
  const float* W2   = (const float*)d_in[18];
  const float* b2   = (const float*)d_in[19];
  const float* gamma= (const float*)d_in[20];
  const float* beta = (const float*)d_in[21];
  float* out = (float*)d_out;

  char* ws = (char*)d_ws;
  const size_t MB = 1024ull * 1024;
  bf16*  bz   = (bf16*) (ws);              // 0-8: z bf16, then a bf16
  f16*   qkh  = (f16*)  (ws + 8 * MB);     // 8-24 (dead after flash)
  f16*   Vt   = (f16*)  (ws + 24 * MB);    // 24-32 (dead after flash)
  bf16*  Op   = (bf16*) (ws + 32 * MB);    // 32-64: flash O partials x4 (live through gemm_wo)
  float* Rp   = (float*)(ws + 64 * MB);    // 64-65: row sums x4 (live through gemm_wo)
  bf16*  PaW  = (bf16*) (ws + 8 * MB);     // Wo partials in dead qkh region (must NOT alias Op!)
  bf16*  PbW  = (bf16*) (ws + 16 * MB);
  bf16*  ffn1 = (bf16*) (ws + 8 * MB);     // 8-40 (PaW/PbW dead after ln_merge; Op dead too)
  bf16*  Pa2  = (bf16*) (ws + 40 * MB);    // FFN2 partials 40-48, 48-56
  bf16*  Pb2  = (bf16*) (ws + 48 * MB);
  char* wp = ws + 74 * MB;
  bf16* wfqp = (bf16*)(wp);
  bf16* wfkp = (bf16*)(wp + 512 * 1024);
  bf16* wfvp = (bf16*)(wp + 1024 * 1024);
  bf16* wqt  = (bf16*)(wp + 1536 * 1024);
  bf16* wkt  = (bf16*)(wp + 2048 * 1024);
  bf16* wvt  = (bf16*)(wp + 2560 * 1024);
  bf16* wc   = (bf16*)(wp + 3072 * 1024);
  bf16* wot  = (bf16*)(wp + 4608 * 1024);
  bf16* w1t  = (bf16*)(wp + 5120 * 1024);
  bf16* w2t  = (bf16*)(wp + 7168 * 1024);
  float* bc  = (float*)(wp + 9216 * 1024);

  conv_t<<<dim3(384, 10), 256, 0, stream>>>(Wo, W1, W2, WQ, WK, WV, WfQ, WfK, WfV,
                                            bfQv, bfKv, bfVv, bQ, bK, bV,
                                            wot, w1t, w2t, wqt, wkt, wvt,
                                            wfqp, wfkp, wfvp, bc);
  gemm_comb<<<dim3(4, 8, 3), 256, 0, stream>>>(wqt, wkt, wvt, wfqp, wfkp, wfvp, wc);

  embed_pe<<<8192, 256, 0, stream>>>(x, emb, bz);

  gemm_qkv<<<dim3(64, 12), 256, 0, stream>>>(bz, wc, bc, qkh, Vt);
  flash_attn<<<dim3(16, 32, 4), 256, 0, stream>>>(qkh, Vt, Op, Rp);

  // Wo GEMM with fused 4-way partial merge (reads Op/Rp; writes PaW/PbW in dead qkh region)
  gemm_wo<<<dim3(64, 4, 2), 256, 0, stream>>>(Op, Rp, wot, PaW, PbW);
  ln_merge<<<2048, 256, 0, stream>>>(PaW, PbW, bo, bz, gamma, beta, nullptr, bz, 0);
  gemm_bt<<<dim3(64, 16), 256, 0, stream>>>(bz, w1t, b1, ffn1, 8192, 2048, 512, 1);
  gemm_part<<<dim3(64, 4, 2), 256, 0, stream>>>(ffn1, w2t, Pa2, Pb2, 512, 2048, 1024);
  ln_merge<<<2048, 256, 0, stream>>>(Pa2, Pb2, b2, bz, gamma, beta, out, nullptr, 1);
}

// Round 12
// 311.655 us; speedup vs baseline: 1.0685x; 1.0303x over previous
//
#include <hip/hip_runtime.h>
#include <math.h>

typedef __bf16 bf16;
typedef __bf16 bf16x8 __attribute__((ext_vector_type(8)));
typedef __bf16 bf16x4 __attribute__((ext_vector_type(4)));
typedef _Float16 f16;
typedef _Float16 f16x8 __attribute__((ext_vector_type(8)));
typedef _Float16 f16x4 __attribute__((ext_vector_type(4)));
typedef _Float16 f16x2 __attribute__((ext_vector_type(2)));
typedef __fp16 h16x2 __attribute__((ext_vector_type(2)));
typedef float f32x4 __attribute__((ext_vector_type(4)));
typedef unsigned int u32;

#define S_LEN 2048
#define QSCALE 0.18033688011112042f   // (1/8)*log2(e), folded into Q weights+bias

#if __has_builtin(__builtin_amdgcn_exp2f)
#define EXP2(x) __builtin_amdgcn_exp2f(x)   // raw v_exp_f32, no OCML denormal guard
#else
#define EXP2(x) exp2f(x)
#endif

__device__ __forceinline__ void gload_lds16(const void* g, void* l) {
  __builtin_amdgcn_global_load_lds((const __attribute__((address_space(1))) u32*)g,
                                   (__attribute__((address_space(3))) u32*)l, 16, 0, 0);
}

// ---------------- embedding + sinusoidal PE (bf16 out only) ----------------
__global__ __launch_bounds__(256) void embed_pe(const int* __restrict__ x,
    const float* __restrict__ emb, bf16* __restrict__ zb)
{
  const int row = blockIdx.x;
  const int s = row & (S_LEN - 1);
  const int tok = x[row];
  const float* e = emb + (size_t)tok * 512;
  bf16* zbr = zb + (size_t)row * 512;
  for (int i = threadIdx.x; i < 512; i += 256) {
    float invf = __expf((float)i * (-9.210340371976184f / 512.0f));
    float ang = (float)s * invf;
    float pe = (i & 1) ? __cosf(ang) : __sinf(ang);
    zbr[i] = (bf16)(e[i] + pe);
  }
}

// ---------------- weight prep: bias (y=9) + copies (y=6..8) + LDS-tiled transposes (y=0..5) ----------------
__global__ __launch_bounds__(256) void conv_t(
    const float* __restrict__ Wo, const float* __restrict__ W1, const float* __restrict__ W2,
    const float* __restrict__ WQ, const float* __restrict__ WK, const float* __restrict__ WV,
    const float* __restrict__ WfQ, const float* __restrict__ WfK, const float* __restrict__ WfV,
    const float* __restrict__ bfQ, const float* __restrict__ bfK, const float* __restrict__ bfV,
    const float* __restrict__ bQ, const float* __restrict__ bK, const float* __restrict__ bV,
    bf16* __restrict__ wot, bf16* __restrict__ w1t, bf16* __restrict__ w2t,
    bf16* __restrict__ wqt, bf16* __restrict__ wkt, bf16* __restrict__ wvt,
    bf16* __restrict__ wfqp, bf16* __restrict__ wfkp, bf16* __restrict__ wfvp,
    float* __restrict__ bc)
{
  __shared__ float T[64][65];
  const int y = blockIdx.y, x = blockIdx.x;
  if (y == 9) {                                   // combined bias, x < 384
    int n = x * 4 + ((int)threadIdx.x >> 6);
    int lane = threadIdx.x & 63;
    int z = n >> 9, hk = n & 511, h = hk >> 6, k = hk & 63;
    const float* bf = z == 0 ? bfQ : (z == 1 ? bfK : bfV);
    const float* W  = z == 0 ? WQ  : (z == 1 ? WK  : WV);
    const float* bH = z == 0 ? bQ  : (z == 1 ? bK  : bV);
    float s = 0.f;
    for (int e = lane; e < 512; e += 64)
      s += bf[e] * W[((size_t)h * 512 + e) * 64 + k];
    #pragma unroll
    for (int m = 1; m < 64; m <<= 1) s += __shfl_xor(s, m, 64);
    if (lane == 0) {
      float v = s + bH[h * 64 + k];
      if (z == 0) v *= QSCALE;
      bc[n] = v;
    }
    return;
  }
  if (y >= 6) {
    if (x >= 256) return;
    int g = x * 256 + threadIdx.x;               // 65536 float4 per tensor
    const float* in = y == 6 ? WfQ : (y == 7 ? WfK : WfV);
    bf16* outp = y == 6 ? wfqp : (y == 7 ? wfkp : wfvp);
    float4 v = *(const float4*)(in + (size_t)g * 4);
    bf16x4 o = {(bf16)v.x, (bf16)v.y, (bf16)v.z, (bf16)v.w};
    *(bf16x4*)(outp + (size_t)g * 4) = o;
    return;
  }
  const int tx = threadIdx.x & 63, ty = threadIdx.x >> 6;
  const float* src; bf16* dst;
  int src_cols, dst_cols; float scale = 1.f;
  if (y == 0) {
    if (x >= 64) return;
    int kt = x & 7, nt = x >> 3;
    src = Wo + (size_t)(kt * 64) * 512 + nt * 64; src_cols = 512;
    dst = wot + (size_t)(nt * 64) * 512 + kt * 64; dst_cols = 512;
  } else if (y == 1) {
    if (x >= 256) return;
    int kt = x & 7, nt = x >> 3;
    src = W1 + (size_t)(kt * 64) * 2048 + nt * 64; src_cols = 2048;
    dst = w1t + (size_t)(nt * 64) * 512 + kt * 64; dst_cols = 512;
  } else if (y == 2) {
    if (x >= 256) return;
    int kt = x & 31, nt = x >> 5;
    src = W2 + (size_t)(kt * 64) * 512 + nt * 64; src_cols = 512;
    dst = w2t + (size_t)(nt * 64) * 2048 + kt * 64; dst_cols = 2048;
  } else {
    if (x >= 64) return;
    const float* W = y == 3 ? WQ : (y == 4 ? WK : WV);
    bf16* o = y == 3 ? wqt : (y == 4 ? wkt : wvt);
    if (y == 3) scale = QSCALE;
    int h = x >> 3, rt = x & 7;
    src = W + (size_t)(h * 512 + rt * 64) * 64; src_cols = 64;
    dst = o + (size_t)(h * 64) * 512 + rt * 64; dst_cols = 512;
  }
  #pragma unroll
  for (int i = 0; i < 16; i++) {
    int rr = i * 4 + ty;
    T[rr][tx] = src[(size_t)rr * src_cols + tx];
  }
  __syncthreads();
  #pragma unroll
  for (int i = 0; i < 16; i++) {
    int rr = i * 4 + ty;
    dst[(size_t)rr * dst_cols + tx] = (bf16)(T[tx][rr] * scale);
  }
}

// ---------------- weight-combine GEMMs (3 in one launch, 128x64 tiles) ----------------
__global__ __launch_bounds__(256) void gemm_comb(
    const bf16* __restrict__ wqt, const bf16* __restrict__ wkt, const bf16* __restrict__ wvt,
    const bf16* __restrict__ wfqp, const bf16* __restrict__ wfkp, const bf16* __restrict__ wfvp,
    bf16* __restrict__ wc)
{
  __shared__ bf16 As[128 * 32];
  __shared__ bf16 Bs[64 * 32];
  const int z = blockIdx.z;
  const bf16* A  = z == 0 ? wqt : (z == 1 ? wkt : wvt);
  const bf16* Bt = z == 0 ? wfqp : (z == 1 ? wfkp : wfvp);
  bf16* outb = wc + (size_t)z * 262144;
  const int tid = threadIdx.x;
  const int wave = tid >> 6, lane = tid & 63, quad = lane >> 4, l16 = lane & 15;
  const int row0 = blockIdx.x * 128, col0 = blockIdx.y * 64;
  const int wm = wave >> 1, wn = wave & 1;
  f32x4 acc[4][2] = {};

  for (int kk = 0; kk < 512; kk += 32) {
    __syncthreads();
    #pragma unroll
    for (int r = 0; r < 2; r++) {
      int c = r * 256 + tid;
      gload_lds16(A + (size_t)(row0 + (c >> 2)) * 512 + kk + (c & 3) * 8, As + c * 8);
    }
    gload_lds16(Bt + (size_t)(col0 + (tid >> 2)) * 512 + kk + (tid & 3) * 8, Bs + tid * 8);
    __syncthreads();
    bf16x8 af[4], bfr[2];
    #pragma unroll
    for (int i = 0; i < 4; i++)
      af[i] = *(const bf16x8*)(As + (wm * 64 + i * 16 + l16) * 32 + quad * 8);
    #pragma unroll
    for (int i = 0; i < 2; i++)
      bfr[i] = *(const bf16x8*)(Bs + (wn * 32 + i * 16 + l16) * 32 + quad * 8);
    #pragma unroll
    for (int mt = 0; mt < 4; mt++)
      #pragma unroll
      for (int nt = 0; nt < 2; nt++)
        acc[mt][nt] = __builtin_amdgcn_mfma_f32_16x16x32_bf16(af[mt], bfr[nt], acc[mt][nt], 0, 0, 0);
  }
  #pragma unroll
  for (int nt = 0; nt < 2; nt++) {
    int col = col0 + wn * 32 + nt * 16 + l16;
    #pragma unroll
    for (int mt = 0; mt < 4; mt++) {
      int rowb = row0 + wm * 64 + mt * 16 + quad * 4;
      #pragma unroll
      for (int i = 0; i < 4; i++)
        outb[(size_t)(rowb + i) * 512 + col] = (bf16)acc[mt][nt][i];
    }
  }
}

// ======== dbuf reg-prefetch GEMM core (128x128 tile, BK=32, 1 barrier/iter) ========
#define GEMM_CORE(A_, Bt_, K_, KK0_, ITERS_)                                            \
  bf16x8 ar0, ar1, br0, br1;                                                            \
  const int c0 = tid, c1 = 256 + tid;                                                   \
  const size_t aoff0 = (size_t)(row0 + (c0 >> 2)) * (K_) + (c0 & 3) * 8;                \
  const size_t aoff1 = (size_t)(row0 + (c1 >> 2)) * (K_) + (c1 & 3) * 8;                \
  const size_t boff0 = (size_t)(col0 + (c0 >> 2)) * (K_) + (c0 & 3) * 8;                \
  const size_t boff1 = (size_t)(col0 + (c1 >> 2)) * (K_) + (c1 & 3) * 8;                \
  ar0 = *(const bf16x8*)((A_) + aoff0 + (KK0_));                                        \
  ar1 = *(const bf16x8*)((A_) + aoff1 + (KK0_));                                        \
  br0 = *(const bf16x8*)((Bt_) + boff0 + (KK0_));                                       \
  br1 = *(const bf16x8*)((Bt_) + boff1 + (KK0_));                                       \
  for (int it = 0; it < (ITERS_); it++) {                                               \
    bf16* AsB = As[it & 1];                                                             \
    bf16* BsB = Bs[it & 1];                                                             \
    *(bf16x8*)(AsB + c0 * 8) = ar0;                                                     \
    *(bf16x8*)(AsB + c1 * 8) = ar1;                                                     \
    *(bf16x8*)(BsB + c0 * 8) = br0;                                                     \
    *(bf16x8*)(BsB + c1 * 8) = br1;                                                     \
    __syncthreads();                                                                    \
    if (it + 1 < (ITERS_)) {                                                            \
      int kk = (KK0_) + (it + 1) * 32;                                                  \
      ar0 = *(const bf16x8*)((A_) + aoff0 + kk);                                        \
      ar1 = *(const bf16x8*)((A_) + aoff1 + kk);                                        \
      br0 = *(const bf16x8*)((Bt_) + boff0 + kk);                                      \
      br1 = *(const bf16x8*)((Bt_) + boff1 + kk);                                      \
    }                                                                                   \
    bf16x8 af[4], bfr[4];                                                               \
    _Pragma("unroll")                                                                   \
    for (int i = 0; i < 4; i++)                                                         \
      af[i] = *(const bf16x8*)(AsB + (wm * 64 + i * 16 + l16) * 32 + quad * 8);         \
    _Pragma("unroll")                                                                   \
    for (int i = 0; i < 4; i++)                                                         \
      bfr[i] = *(const bf16x8*)(BsB + (wn * 64 + i * 16 + l16) * 32 + quad * 8);        \
    _Pragma("unroll")                                                                   \
    for (int mt = 0; mt < 4; mt++)                                                      \
      _Pragma("unroll")                                                                 \
      for (int nt = 0; nt < 4; nt++)                                                    \
        acc[mt][nt] = __builtin_amdgcn_mfma_f32_16x16x32_bf16(af[mt], bfr[nt], acc[mt][nt], 0, 0, 0); \
  }

// ---------------- GEMM 128x128 (bias, optional relu, bf16 out; FFN1) ----------------
// (256,2): occupancy is LDS/VGPR-capped at ~2 blocks/CU anyway; lowering the compiler's
// target licenses longer live ranges -> prefetch/ds_read/MFMA interleave (flash R7 lesson).
__global__ __launch_bounds__(256, 2) void gemm_bt(
    const bf16* __restrict__ A, const bf16* __restrict__ Bt,
    const float* __restrict__ bias, bf16* __restrict__ outb,
    int M, int N, int K, int relu)
{
  __shared__ bf16 As[2][4096];
  __shared__ bf16 Bs[2][4096];
  const int tid = threadIdx.x;
  const int wave = tid >> 6, lane = tid & 63, quad = lane >> 4, l16 = lane & 15;
  const int row0 = blockIdx.x * 128, col0 = blockIdx.y * 128;
  const int wm = wave >> 1, wn = wave & 1;
  f32x4 acc[4][4] = {};
  GEMM_CORE(A, Bt, K, 0, K / 32)

  #pragma unroll
  for (int nt = 0; nt < 4; nt++) {
    int col = col0 + wn * 64 + nt * 16 + l16;
    float bv = bias[col];
    #pragma unroll
    for (int mt = 0; mt < 4; mt++) {
      int rowb = row0 + wm * 64 + mt * 16 + quad * 4;
      #pragma unroll
      for (int i = 0; i < 4; i++) {
        float v = acc[mt][nt][i] + bv;
        if (relu) v = fmaxf(v, 0.f);
        outb[(size_t)(rowb + i) * N + col] = (bf16)v;
      }
    }
  }
}

// ---------------- QKV GEMM: N=1536, writes qk f16[row][1024] + Vt f16[bh][dv][2048] ----------------
__global__ __launch_bounds__(256, 2) void gemm_qkv(
    const bf16* __restrict__ A, const bf16* __restrict__ Bt,
    const float* __restrict__ bias, f16* __restrict__ qk, f16* __restrict__ Vt)
{
  __shared__ bf16 As[2][4096];
  __shared__ bf16 Bs[2][4096];
  const int tid = threadIdx.x;
  const int wave = tid >> 6, lane = tid & 63, quad = lane >> 4, l16 = lane & 15;
  const int row0 = blockIdx.x * 128, col0 = blockIdx.y * 128;
  const int wm = wave >> 1, wn = wave & 1;
  f32x4 acc[4][4] = {};
  GEMM_CORE(A, Bt, 512, 0, 16)

  #pragma unroll
  for (int nt = 0; nt < 4; nt++) {
    int col = col0 + wn * 64 + nt * 16 + l16;
    float bv = bias[col];
    if (col < 1024) {
      #pragma unroll
      for (int mt = 0; mt < 4; mt++) {
        int rowb = row0 + wm * 64 + mt * 16 + quad * 4;
        #pragma unroll
        for (int i = 0; i < 4; i++)
          qk[(size_t)(rowb + i) * 1024 + col] = (f16)(acc[mt][nt][i] + bv);
      }
    } else {
      int h = (col - 1024) >> 6, dv = col & 63;
      #pragma unroll
      for (int mt = 0; mt < 4; mt++) {
        int rowb = row0 + wm * 64 + mt * 16 + quad * 4;
        int b = rowb >> 11, s = rowb & 2047;
        f16x4 vv;
        #pragma unroll
        for (int i = 0; i < 4; i++) vv[i] = (f16)(acc[mt][nt][i] + bv);
        *(f16x4*)(Vt + ((size_t)((b * 8 + h) * 64 + dv)) * 2048 + s) = vv;
      }
    }
  }
}

// ---------------- split-K partial GEMM -> bf16 partials (FFN2, 2-way) ----------------
__global__ __launch_bounds__(256, 2) void gemm_part(
    const bf16* __restrict__ A, const bf16* __restrict__ Bt,
    bf16* __restrict__ Pa, bf16* __restrict__ Pb, int N, int K, int Kh)
{
  __shared__ bf16 As[2][4096];
  __shared__ bf16 Bs[2][4096];
  const int tid = threadIdx.x;
  const int wave = tid >> 6, lane = tid & 63, quad = lane >> 4, l16 = lane & 15;
  const int row0 = blockIdx.x * 128, col0 = blockIdx.y * 128;
  const int wm = wave >> 1, wn = wave & 1;
  const int kk0 = blockIdx.z * Kh;
  bf16* P = blockIdx.z ? Pb : Pa;
  f32x4 acc[4][4] = {};
  GEMM_CORE(A, Bt, K, kk0, Kh / 32)

  #pragma unroll
  for (int nt = 0; nt < 4; nt++) {
    int col = col0 + wn * 64 + nt * 16 + l16;
    #pragma unroll
    for (int mt = 0; mt < 4; mt++) {
      int rowb = row0 + wm * 64 + mt * 16 + quad * 4;
      #pragma unroll
      for (int i = 0; i < 4; i++)
        P[(size_t)(rowb + i) * N + col] = (bf16)acc[mt][nt][i];
    }
  }
}

// ---------------- Wo GEMM with fused attention-partial merge ----------------
__global__ __launch_bounds__(256, 2) void gemm_wo(
    const bf16* __restrict__ Op, const float* __restrict__ Rp,
    const bf16* __restrict__ Bt, bf16* __restrict__ Pa, bf16* __restrict__ Pb)
{
  __shared__ bf16 As[2][4096];
  __shared__ bf16 Bs[2][4096];
  const int tid = threadIdx.x;
  const int wave = tid >> 6, lane = tid & 63, quad = lane >> 4, l16 = lane & 15;
  const int row0 = blockIdx.x * 128, col0 = blockIdx.y * 128;
  const int wm = wave >> 1, wn = wave & 1;
  const int kk0 = blockIdx.z * 256;
  bf16* P = blockIdx.z ? Pb : Pa;
  f32x4 acc[4][4] = {};

  const int c0 = tid, c1 = 256 + tid;
  const int r0 = row0 + (c0 >> 2), r1 = r0 + 64;
  const int b0 = r0 >> 11, s0 = r0 & 2047;
  const int b1 = r1 >> 11, s1 = r1 & 2047;
  const int ccol = (c0 & 3) * 8;
  const int h0 = kk0 >> 6;
  const size_t boff0 = (size_t)(col0 + (c0 >> 2)) * 512 + ccol;
  const size_t boff1 = (size_t)(col0 + 64 + (c0 >> 2)) * 512 + ccol;

  float inv0[4], inv1[4];
  #pragma unroll
  for (int hh = 0; hh < 4; hh++) {
    int hg = h0 + hh;
    int ra = (b0 * 8 + hg) * 2048 + s0;
    float r = (Rp[ra] + Rp[65536 + ra]) + (Rp[131072 + ra] + Rp[196608 + ra]);
    inv0[hh] = 1.f / r;
    int rb = (b1 * 8 + hg) * 2048 + s1;
    r = (Rp[rb] + Rp[65536 + rb]) + (Rp[131072 + rb] + Rp[196608 + rb]);
    inv1[hh] = 1.f / r;
  }

  bf16x8 p0q[4], p1q[4], br0, br1;
  {
    int hg = h0, dv = ccol;
    size_t ia0 = ((size_t)(b0 * 8 + hg) * 2048 + s0) * 64 + dv;
    size_t ia1 = ((size_t)(b1 * 8 + hg) * 2048 + s1) * 64 + dv;
    #pragma unroll
    for (int q = 0; q < 4; q++) {
      p0q[q] = *(const bf16x8*)(Op + q * 4194304ull + ia0);
      p1q[q] = *(const bf16x8*)(Op + q * 4194304ull + ia1);
    }
    br0 = *(const bf16x8*)(Bt + boff0 + kk0);
    br1 = *(const bf16x8*)(Bt + boff1 + kk0);
  }

  for (int it = 0; it < 8; it++) {
    bf16* AsB = As[it & 1];
    bf16* BsB = Bs[it & 1];
    const float iv0 = inv0[it >> 1];
    const float iv1 = inv1[it >> 1];
    bf16x8 a0v;
    bf16x8 a1v;
    #pragma unroll
    for (int i = 0; i < 8; i++) {
      float v0 = ((float)p0q[0][i] + (float)p0q[1][i]) + ((float)p0q[2][i] + (float)p0q[3][i]);
      float v1 = ((float)p1q[0][i] + (float)p1q[1][i]) + ((float)p1q[2][i] + (float)p1q[3][i]);
      a0v[i] = (bf16)(v0 * iv0);
      a1v[i] = (bf16)(v1 * iv1);
    }
    *(bf16x8*)(AsB + c0 * 8) = a0v;
    *(bf16x8*)(AsB + c1 * 8) = a1v;
    *(bf16x8*)(BsB + c0 * 8) = br0;
    *(bf16x8*)(BsB + c1 * 8) = br1;
    __syncthreads();
    if (it < 7) {
      int itn = it + 1;
      int kk = kk0 + itn * 32;
      int hg = h0 + (itn >> 1);
      int dv = (itn & 1) * 32 + ccol;
      size_t ia0 = ((size_t)(b0 * 8 + hg) * 2048 + s0) * 64 + dv;
      size_t ia1 = ((size_t)(b1 * 8 + hg) * 2048 + s1) * 64 + dv;
      #pragma unroll
      for (int q = 0; q < 4; q++) {
        p0q[q] = *(const bf16x8*)(Op + q * 4194304ull + ia0);
        p1q[q] = *(const bf16x8*)(Op + q * 4194304ull + ia1);
      }
      br0 = *(const bf16x8*)(Bt + boff0 + kk);
      br1 = *(const bf16x8*)(Bt + boff1 + kk);
    }
    bf16x8 af[4], bfr[4];
    #pragma unroll
    for (int i = 0; i < 4; i++)
      af[i] = *(const bf16x8*)(AsB + (wm * 64 + i * 16 + l16) * 32 + quad * 8);
    #pragma unroll
    for (int i = 0; i < 4; i++)
      bfr[i] = *(const bf16x8*)(BsB + (wn * 64 + i * 16 + l16) * 32 + quad * 8);
    #pragma unroll
    for (int mt = 0; mt < 4; mt++)
      #pragma unroll
      for (int nt = 0; nt < 4; nt++)
        acc[mt][nt] = __builtin_amdgcn_mfma_f32_16x16x32_bf16(af[mt], bfr[nt], acc[mt][nt], 0, 0, 0);
  }

  #pragma unroll
  for (int nt = 0; nt < 4; nt++) {
    int col = col0 + wn * 64 + nt * 16 + l16;
    #pragma unroll
    for (int mt = 0; mt < 4; mt++) {
      int rowb = row0 + wm * 64 + mt * 16 + quad * 4;
      #pragma unroll
      for (int i = 0; i < 4; i++)
        P[(size_t)(rowb + i) * 512 + col] = (bf16)acc[mt][nt][i];
    }
  }
}

// ---------------- flash attention: 32 q/wave, split-K 4, dbuf, rsum via ones-MFMA ----------------
// qk: [8192][1024] f16; Vt: [32 bh][64 dv][2048 s] f16. Grid (16 qtile, 32 bh, 4 quarter).
__global__ __launch_bounds__(256, 2) void flash_attn(
    const f16* __restrict__ qk, const f16* __restrict__ Vt,
    bf16* __restrict__ Op, float* __restrict__ Rp)
{
  __shared__ f16 Ks[2][4096];   // [key][dk], 16B chunks XOR-swizzled by row&7
  __shared__ f16 Vs[2][4096];   // [dv][key], same swizzle
  const int bh = blockIdx.y, b = bh >> 3, h = bh & 7;
  const int q0 = blockIdx.x * 128;
  const int quarter = blockIdx.z;
  const int tid = threadIdx.x;
  const int wave = tid >> 6, lane = tid & 63, quad = lane >> 4, l16 = lane & 15;

  const f16* Qb = qk + ((size_t)b * S_LEN) * 1024 + h * 64;
  const f16* Kb = Qb + 512;
  const f16* Vtb = Vt + ((size_t)bh * 64) * 2048;
  const int key0 = quarter * 512;

  f16x8 qf[2][2];
  #pragma unroll
  for (int f = 0; f < 2; f++) {
    int qrow = q0 + wave * 32 + f * 16 + l16;
    #pragma unroll
    for (int kh = 0; kh < 2; kh++)
      qf[f][kh] = *(const f16x8*)(Qb + (size_t)qrow * 1024 + kh * 32 + quad * 8);
  }

  f32x4 O[2][4] = {};            // [f][mt]: O^T row=dv, col=q
  f32x4 Osum[2] = {};            // rsum accumulator via ones-MFMA
  const f16x4 onesA = {(f16)1.f, (f16)1.f, (f16)1.f, (f16)1.f};
  const int swz = l16 & 7;

  f16x8 kreg[2], vreg[2];
  const int srow = tid >> 3, soff = tid & 7;
  const int srow1 = srow + 32;

  {
    int kb = key0;
    kreg[0] = *(const f16x8*)(Kb + (size_t)(kb + srow) * 1024 + soff * 8);
    vreg[0] = *(const f16x8*)(Vtb + (size_t)srow * 2048 + kb + soff * 8);
    kreg[1] = *(const f16x8*)(Kb + (size_t)(kb + srow1) * 1024 + soff * 8);
    vreg[1] = *(const f16x8*)(Vtb + (size_t)srow1 * 2048 + kb + soff * 8);
  }

  for (int c = 0; c < 8; c++) {
    f16* KsB = Ks[c & 1];
    f16* VsB = Vs[c & 1];
    *(f16x8*)(KsB + srow * 64 + ((soff ^ (srow & 7)) * 8)) = kreg[0];
    *(f16x8*)(VsB + srow * 64 + ((soff ^ (srow & 7)) * 8)) = vreg[0];
    *(f16x8*)(KsB + srow1 * 64 + ((soff ^ (srow1 & 7)) * 8)) = kreg[1];
    *(f16x8*)(VsB + srow1 * 64 + ((soff ^ (srow1 & 7)) * 8)) = vreg[1];
    __syncthreads();
    if (c < 7) {
      int kb = key0 + (c + 1) * 64;
      kreg[0] = *(const f16x8*)(Kb + (size_t)(kb + srow) * 1024 + soff * 8);
      vreg[0] = *(const f16x8*)(Vtb + (size_t)srow * 2048 + kb + soff * 8);
      kreg[1] = *(const f16x8*)(Kb + (size_t)(kb + srow1) * 1024 + soff * 8);
      vreg[1] = *(const f16x8*)(Vtb + (size_t)srow1 * 2048 + kb + soff * 8);
    }

    #pragma unroll
    for (int nt = 0; nt < 4; nt++) {
      const f16* kp = KsB + (nt * 16 + l16) * 64;
      f16x8 kf0 = *(const f16x8*)(kp + ((quad ^ swz) * 8));
      f16x8 kf1 = *(const f16x8*)(kp + (((4 + quad) ^ swz) * 8));
      f16x4 pf[2];
      f32x4 a0 = {}, a1 = {};
      __builtin_amdgcn_s_setprio(1);
      a0 = __builtin_amdgcn_mfma_f32_16x16x32_f16(kf0, qf[0][0], a0, 0, 0, 0);
      a0 = __builtin_amdgcn_mfma_f32_16x16x32_f16(kf1, qf[0][1], a0, 0, 0, 0);
      a1 = __builtin_amdgcn_mfma_f32_16x16x32_f16(kf0, qf[1][0], a1, 0, 0, 0);
      a1 = __builtin_amdgcn_mfma_f32_16x16x32_f16(kf1, qf[1][1], a1, 0, 0, 0);
      __builtin_amdgcn_s_setprio(0);
      #pragma unroll
      for (int f = 0; f < 2; f++) {
        const f32x4& a = f == 0 ? a0 : a1;
        float e0 = EXP2(a[0]);
        float e1 = EXP2(a[1]);
        float e2 = EXP2(a[2]);
        float e3 = EXP2(a[3]);
        h16x2 lo = __builtin_amdgcn_cvt_pkrtz(e0, e1);
        h16x2 hi = __builtin_amdgcn_cvt_pkrtz(e2, e3);
        f16x2 lo2 = __builtin_bit_cast(f16x2, lo);
        f16x2 hi2 = __builtin_bit_cast(f16x2, hi);
        pf[f] = __builtin_shufflevector(lo2, hi2, 0, 1, 2, 3);
        Osum[f] = __builtin_amdgcn_mfma_f32_16x16x16f16(onesA, pf[f], Osum[f], 0, 0, 0);
      }
      int vchunk = nt * 2 + (quad >> 1);
      __builtin_amdgcn_s_setprio(1);
      #pragma unroll
      for (int mt = 0; mt < 4; mt++) {
        const f16* vp = VsB + (mt * 16 + l16) * 64 + ((vchunk ^ swz) * 8) + (quad & 1) * 4;
        f16x4 vf = *(const f16x4*)vp;
        #pragma unroll
        for (int f = 0; f < 2; f++)
          O[f][mt] = __builtin_amdgcn_mfma_f32_16x16x16f16(vf, pf[f], O[f][mt], 0, 0, 0);
      }
      __builtin_amdgcn_s_setprio(0);
    }
  }

  // store un-normalized partials (transpose through per-wave XOR-swizzled LDS regions)
  #pragma unroll
  for (int f = 0; f < 2; f++) {
    bf16* ob = (f == 0 ? (bf16*)&Ks[0][0] : (bf16*)&Vs[0][0]) + wave * 1024;
    #pragma unroll
    for (int mt = 0; mt < 4; mt++) {
      bf16x4 w;
      #pragma unroll
      for (int i = 0; i < 4; i++) w[i] = (bf16)O[f][mt][i];
      int chunk = mt * 2 + (quad >> 1);
      *(bf16x4*)(ob + l16 * 64 + ((chunk ^ (l16 & 7)) << 3) + (quad & 1) * 4) = w;
    }
  }
  asm volatile("s_waitcnt lgkmcnt(0)" ::: "memory");
  const size_t obase = (size_t)(quarter * 32 + bh) * 2048;
  #pragma unroll
  for (int f = 0; f < 2; f++) {
    const bf16* ob = (f == 0 ? (const bf16*)&Ks[0][0] : (const bf16*)&Vs[0][0]) + wave * 1024;
    int row = lane >> 2, cc = (lane & 3) * 2;
    bf16x8 o0 = *(const bf16x8*)(ob + row * 64 + ((cc ^ (row & 7)) << 3));
    bf16x8 o1 = *(const bf16x8*)(ob + row * 64 + (((cc + 1) ^ (row & 7)) << 3));
    size_t g = (obase + q0 + wave * 32 + f * 16 + row) * 64 + (lane & 3) * 16;
    *(bf16x8*)(Op + g) = o0;
    *(bf16x8*)(Op + g + 8) = o1;
    if (quad == f)
      Rp[obase + q0 + wave * 32 + f * 16 + l16] = Osum[f][0];
  }
}

// ---------------- LN merge: (Pa+Pb+badd+resid[bf16]) -> LN -> outf? outb? relu? ----------------
__global__ __launch_bounds__(256) void ln_merge(const bf16* __restrict__ Pa,
    const bf16* __restrict__ Pb, const float* __restrict__ badd,
    const bf16* __restrict__ resid, const float* __restrict__ gamma,
    const float* __restrict__ beta, float* __restrict__ outf,
    bf16* __restrict__ outb, int relu)
{
  const int row = blockIdx.x * 4 + (threadIdx.x >> 6);
  const int lane = threadIdx.x & 63;
  const size_t base = (size_t)row * 512;
  const int e0 = lane * 8;
  bf16x8 pa = *(const bf16x8*)(Pa + base + e0);
  bf16x8 pb = *(const bf16x8*)(Pb + base + e0);
  bf16x8 rr = *(const bf16x8*)(resid + base + e0);
  float4 C0 = *(const float4*)(badd + e0);
  float4 C1 = *(const float4*)(badd + e0 + 4);
  float v[8];
  v[0] = (float)pa[0] + (float)pb[0] + (float)rr[0] + C0.x;
  v[1] = (float)pa[1] + (float)pb[1] + (float)rr[1] + C0.y;
  v[2] = (float)pa[2] + (float)pb[2] + (float)rr[2] + C0.z;
  v[3] = (float)pa[3] + (float)pb[3] + (float)rr[3] + C0.w;
  v[4] = (float)pa[4] + (float)pb[4] + (float)rr[4] + C1.x;
  v[5] = (float)pa[5] + (float)pb[5] + (float)rr[5] + C1.y;
  v[6] = (float)pa[6] + (float)pb[6] + (float)rr[6] + C1.z;
  v[7] = (float)pa[7] + (float)pb[7] + (float)rr[7] + C1.w;
  float s = 0.f;
  #pragma unroll
  for (int i = 0; i < 8; i++) s += v[i];
  #pragma unroll
  for (int m = 1; m < 64; m <<= 1) s += __shfl_xor(s, m, 64);
  float mu = s * (1.f / 512.f);
  float d[8], q = 0.f;
  #pragma unroll
  for (int i = 0; i < 8; i++) { d[i] = v[i] - mu; q += d[i] * d[i]; }
  #pragma unroll
  for (int m = 1; m < 64; m <<= 1) q += __shfl_xor(q, m, 64);
  float rsn = rsqrtf(q * (1.f / 512.f) + 1e-5f);
  float4 g0 = *(const float4*)(gamma + e0);
  float4 g1 = *(const float4*)(gamma + e0 + 4);
  float4 b0 = *(const float4*)(beta + e0);
  float4 b1 = *(const float4*)(beta + e0 + 4);
  float y[8];
  y[0] = d[0] * rsn * g0.x + b0.x; y[1] = d[1] * rsn * g0.y + b0.y;
  y[2] = d[2] * rsn * g0.z + b0.z; y[3] = d[3] * rsn * g0.w + b0.w;
  y[4] = d[4] * rsn * g1.x + b1.x; y[5] = d[5] * rsn * g1.y + b1.y;
  y[6] = d[6] * rsn * g1.z + b1.z; y[7] = d[7] * rsn * g1.w + b1.w;
  if (relu) {
    #pragma unroll
    for (int i = 0; i < 8; i++) y[i] = fmaxf(y[i], 0.f);
  }
  if (outf) {
    float4 o0 = {y[0], y[1], y[2], y[3]}, o1 = {y[4], y[5], y[6], y[7]};
    *(float4*)(outf + base + e0) = o0;
    *(float4*)(outf + base + e0 + 4) = o1;
  }
  if (outb) {
    bf16x8 ob;
    #pragma unroll
    for (int i = 0; i < 8; i++) ob[i] = (bf16)y[i];
    *(bf16x8*)(outb + base + e0) = ob;
  }
}

extern "C" void kernel_launch(void* const* d_in, const int* in_sizes, int n_in,
                              void* d_out, int out_size, void* d_ws, size_t ws_size,
                              hipStream_t stream)
{
  const int*   x    = (const int*)  d_in[0];
  const float* emb  = (const float*)d_in[1];
  const float* WfQ  = (const float*)d_in[2];
  const float* bfQv = (const float*)d_in[3];
  const float* WfK  = (const float*)d_in[4];
  const float* bfKv = (const float*)d_in[5];
  const float* WfV  = (const float*)d_in[6];
  const float* bfVv = (const float*)d_in[7];
  const float* WQ   = (const float*)d_in[8];
  const float* bQ   = (const float*)d_in[9];
  const float* WK   = (const float*)d_in[10];
  const float* bK   = (const float*)d_in[11];
  const float* WV   = (const float*)d_in[12];
  const float* bV   = (const float*)d_in[13];
  const float* Wo   = (const float*)d_in[14];
  const float* bo   = (const float*)d_in[15];
  const float* W1   = (const float*)d_in[16];
  const float* b1   = (const float*)d_in[17];
  const float* W2   = (const float*)d_in[18];
  const float* b2   = (const float*)d_in[19];
  const float* gamma= (const float*)d_in[20];
  const float* beta = (const float*)d_in[21];
  float* out = (float*)d_out;

  char* ws = (char*)d_ws;
  const size_t MB = 1024ull * 1024;
  bf16*  bz   = (bf16*) (ws);              // 0-8: z bf16, then a bf16
  f16*   qkh  = (f16*)  (ws + 8 * MB);     // 8-24 (dead after flash)
  f16*   Vt   = (f16*)  (ws + 24 * MB);    // 24-32 (dead after flash)
  bf16*  Op   = (bf16*) (ws + 32 * MB);    // 32-64: flash O partials x4 (live through gemm_wo)
  float* Rp   = (float*)(ws + 64 * MB);    // 64-65: row sums x4 (live through gemm_wo)
  bf16*  PaW  = (bf16*) (ws + 8 * MB);     // Wo partials in dead qkh region (must NOT alias Op!)
  bf16*  PbW  = (bf16*) (ws + 16 * MB);
  bf16*  ffn1 = (bf16*) (ws + 8 * MB);     // 8-40 (PaW/PbW dead after ln_merge; Op dead too)
  bf16*  Pa2  = (bf16*) (ws + 40 * MB);    // FFN2 partials 40-48, 48-56
  bf16*  Pb2  = (bf16*) (ws + 48 * MB);
  char* wp = ws + 74 * MB;
  bf16* wfqp = (bf16*)(wp);
  bf16* wfkp = (bf16*)(wp + 512 * 1024);
  bf16* wfvp = (bf16*)(wp + 1024 * 1024);
  bf16* wqt  = (bf16*)(wp + 1536 * 1024);
  bf16* wkt  = (bf16*)(wp + 2048 * 1024);
  bf16* wvt  = (bf16*)(wp + 2560 * 1024);
  bf16* wc   = (bf16*)(wp + 3072 * 1024);
  bf16* wot  = (bf16*)(wp + 4608 * 1024);
  bf16* w1t  = (bf16*)(wp + 5120 * 1024);
  bf16* w2t  = (bf16*)(wp + 7168 * 1024);
  float* bc  = (float*)(wp + 9216 * 1024);

  conv_t<<<dim3(384, 10), 256, 0, stream>>>(Wo, W1, W2, WQ, WK, WV, WfQ, WfK, WfV,
                                            bfQv, bfKv, bfVv, bQ, bK, bV,
                                            wot, w1t, w2t, wqt, wkt, wvt,
                                            wfqp, wfkp, wfvp, bc);
  gemm_comb<<<dim3(4, 8, 3), 256, 0, stream>>>(wqt, wkt, wvt, wfqp, wfkp, wfvp, wc);

  embed_pe<<<8192, 256, 0, stream>>>(x, emb, bz);

  gemm_qkv<<<dim3(64, 12), 256, 0, stream>>>(bz, wc, bc, qkh, Vt);
  flash_attn<<<dim3(16, 32, 4), 256, 0, stream>>>(qkh, Vt, Op, Rp);

  // Wo GEMM with fused 4-way partial merge (reads Op/Rp; writes PaW/PbW in dead qkh region)
  gemm_wo<<<dim3(64, 4, 2), 256, 0, stream>>>(Op, Rp, wot, PaW, PbW);
  ln_merge<<<2048, 256, 0, stream>>>(PaW, PbW, bo, bz, gamma, beta, nullptr, bz, 0);
  gemm_bt<<<dim3(64, 16), 256, 0, stream>>>(bz, w1t, b1, ffn1, 8192, 2048, 512, 1);
  gemm_part<<<dim3(64, 4, 2), 256, 0, stream>>>(ffn1, w2t, Pa2, Pb2, 512, 2048, 1024);
  ln_merge<<<2048, 256, 0, stream>>>(Pa2, Pb2, b2, bz, gamma, beta, out, nullptr, 1);
}